// Round 2
// baseline (3529.285 us; speedup 1.0000x reference)
//
#include <hip/hip_runtime.h>
#include <hip/hip_bf16.h>
#include <stdint.h>

// Problem constants
#define NN 100000   // nodes
#define RR 200      // relations
#define DD 200      // dim
#define BB 30       // bases
#define LL 2        // layers
#define EE 800000   // edges

// Padded GEMM geometry
#define KP 224      // K padded (7 x 32)
#define NP 208      // N padded (13 x 16)
#define XP 208      // xb row pitch (bf16)
#define AP 232      // LDS A-tile pitch (bf16)
#define TE 64       // edges per tile
#define MSGP 224    // msg row pitch (bf16) -> 448B = 7 lines
#define MAXTILES 12700

using bf16x8 = __attribute__((ext_vector_type(8))) short;
using f32x4  = __attribute__((ext_vector_type(4))) float;

// Workspace byte offsets. Fallback (atomic) path touches only < OFF_POS.
#define OFF_NORM   0ull          // E f32
#define OFF_SORT   3200000ull    // E i32
#define OFF_CNT    6400000ull    // 4KB rel counters: cnt@0, relStart@256, relCursor@512, tileOff@768
#define OFF_XB     6404096ull    // N*XP bf16 (deg8 20MB aliases transiently)
#define OFF_WT     48004096ull   // R*NP*KP bf16
#define OFF_ROOTT  66640896ull   // NP*KP bf16
#define OFF_POS    66734080ull   // E i32 (dst-sorted slot per edge)
#define OFF_DSTCNT 69934080ull   // N i32
#define OFF_DSTST  70334080ull   // (N+1) i32
#define OFF_CUR    70734096ull   // N i32
#define OFF_BLK    71134096ull   // 512 i32
#define OFF_MSG    71136144ull   // E*MSGP bf16 = 358.4MB
#define WS_NEEDED  429536144ull

static __device__ __forceinline__ short f2bf(float v) {
    union { __hip_bfloat16 h; short s; } u;
    u.h = __float2bfloat16(v);
    return u.s;
}
static __device__ __forceinline__ unsigned pk2(float a, float b) {
    return (unsigned)(unsigned short)f2bf(a) | ((unsigned)(unsigned short)f2bf(b) << 16);
}

// ---- counts: per-(dst,rel) deg, per-rel histogram, per-dst histogram ----
__global__ void kCount(const int* __restrict__ ei, const int* __restrict__ et,
                       unsigned int* __restrict__ deg8, int* __restrict__ cnt,
                       int* __restrict__ dstCnt, int big) {
    int e = blockIdx.x * 256 + threadIdx.x;
    if (e >= EE) return;
    int d = ei[EE + e];
    int t = et[e];
    int comb = d * RR + t;
    atomicAdd(&deg8[comb >> 2], 1u << ((comb & 3) * 8));
    atomicAdd(&cnt[t], 1);
    if (big) atomicAdd(&dstCnt[d], 1);
}

// ---- tiny serial scan over relations ----
__global__ void kScan(int* __restrict__ cnt) {
    __shared__ int c[RR];
    int tid = threadIdx.x;
    for (int r = tid; r < RR; r += 64) c[r] = cnt[r];
    __syncthreads();
    if (tid == 0) {
        int s = 0, ts = 0;
        for (int r = 0; r < RR; ++r) {
            cnt[256 + r] = s;
            cnt[512 + r] = s;
            cnt[768 + r] = ts;
            s += c[r];
            ts += (c[r] + TE - 1) / TE;
        }
        cnt[256 + RR] = s;
        cnt[768 + RR] = ts;
    }
}

// ---- 3-kernel exclusive scan of dstCnt[N] -> dstStart[N+1] ----
__global__ void kScanBlk(const int* __restrict__ dstCnt, int* __restrict__ dstStart,
                         int* __restrict__ blkSum) {
    __shared__ int s[256];
    int t = threadIdx.x, i = blockIdx.x * 256 + t;
    int v = (i < NN) ? dstCnt[i] : 0;
    s[t] = v;
    __syncthreads();
    #pragma unroll
    for (int off = 1; off < 256; off <<= 1) {
        int x = (t >= off) ? s[t - off] : 0;
        __syncthreads();
        s[t] += x;
        __syncthreads();
    }
    if (i < NN) dstStart[i] = s[t] - v;
    if (t == 255) blkSum[blockIdx.x] = s[255];
}
__global__ void kScanTop(int* __restrict__ blkSum, int nblk) {
    __shared__ int s[512];
    int t = threadIdx.x;
    int v = (t < nblk) ? blkSum[t] : 0;
    s[t] = v;
    __syncthreads();
    #pragma unroll
    for (int off = 1; off < 512; off <<= 1) {
        int x = (t >= off) ? s[t - off] : 0;
        __syncthreads();
        s[t] += x;
        __syncthreads();
    }
    if (t < nblk) blkSum[t] = s[t] - v;
}
__global__ void kScanAdd(const int* __restrict__ dstCnt, int* __restrict__ dstStart,
                         const int* __restrict__ blkSum) {
    int i = blockIdx.x * 256 + threadIdx.x;
    if (i >= NN) return;
    int v = dstStart[i] + blkSum[blockIdx.x];
    dstStart[i] = v;
    if (i == NN - 1) dstStart[NN] = v + dstCnt[i];
}

// ---- per-edge norm + counting-sort by relation + dst-slot assignment ----
__global__ void kNormScatter(const int* __restrict__ ei, const int* __restrict__ et,
                             const unsigned int* __restrict__ deg8, int* __restrict__ cnt,
                             const int* __restrict__ dstStart, int* __restrict__ cur,
                             float* __restrict__ norm, int* __restrict__ sortedE,
                             int* __restrict__ posDst, int big) {
    int e = blockIdx.x * 256 + threadIdx.x;
    if (e >= EE) return;
    int d = ei[EE + e];
    int t = et[e];
    int comb = d * RR + t;
    unsigned int deg = (deg8[comb >> 2] >> ((comb & 3) * 8)) & 0xffu;
    norm[e] = 1.0f / (float)(deg ? deg : 1u);
    int pos = atomicAdd(&cnt[512 + t], 1);
    sortedE[pos] = e;
    if (big) posDst[e] = dstStart[d] + atomicAdd(&cur[d], 1);
}

// ---- fp32 [N,DD] -> bf16 [N,XP] (fallback path only) ----
__global__ void kConvert(const float* __restrict__ x, short* __restrict__ xb, int doRelu) {
    int idx = blockIdx.x * 256 + threadIdx.x;
    if (idx >= NN * XP) return;
    int i = idx / XP, col = idx - i * XP;
    float v = 0.0f;
    if (col < DD) {
        v = x[i * DD + col];
        if (doRelu) v = fmaxf(v, 0.0f);
    }
    xb[idx] = (col < DD) ? f2bf(v) : (short)0;
}

__global__ void kRelu(float* __restrict__ y) {
    int idx = blockIdx.x * 256 + threadIdx.x;
    if (idx < NN * DD) y[idx] = fmaxf(y[idx], 0.0f);
}

// ---- Wt[r][n][k] = sum_b comp[r][b]*bases[b][k][n] (coalesced b-outer) ----
__global__ void kW(const float* __restrict__ comp, const float* __restrict__ bases,
                   short* __restrict__ Wt) {
    __shared__ float compS[BB];
    __shared__ short wt[32 * 209];
    int kt = blockIdx.x;   // 0..6
    int r  = blockIdx.y;   // 0..199
    int tid = threadIdx.x;
    if (tid < BB) compS[tid] = comp[r * BB + tid];
    __syncthreads();
    float acc[26];
    int   off[26];
    bool  val[26];
    #pragma unroll
    for (int p = 0; p < 26; ++p) {
        int idx = tid + p * 256;            // < 32*208 = 6656
        int kk = idx / NP, n = idx - kk * NP;
        int k = kt * 32 + kk;
        val[p] = (k < DD) && (n < DD);
        off[p] = k * DD + n;
        acc[p] = 0.0f;
    }
    for (int b = 0; b < BB; ++b) {
        float cb = compS[b];
        const float* bp = bases + (size_t)b * DD * DD;
        #pragma unroll
        for (int p = 0; p < 26; ++p)
            if (val[p]) acc[p] += cb * bp[off[p]];
    }
    #pragma unroll
    for (int p = 0; p < 26; ++p) {
        int idx = tid + p * 256;
        int kk = idx / NP, n = idx - kk * NP;
        wt[kk * 209 + n] = f2bf(acc[p]);
    }
    __syncthreads();
    for (int idx = tid; idx < NP * 32; idx += 256) {
        int n = idx >> 5, kk = idx & 31;
        Wt[((size_t)r * NP + n) * KP + kt * 32 + kk] = wt[kk * 209 + n];
    }
}

// ---- rootT[n][k] = root[k][n] ----
__global__ void kRootT(const float* __restrict__ root, short* __restrict__ rootT) {
    int idx = blockIdx.x * 256 + threadIdx.x;
    if (idx >= NP * KP) return;
    int n = idx / KP, k = idx - n * KP;
    rootT[idx] = (n < DD && k < DD) ? f2bf(root[k * DD + n]) : (short)0;
}

// ---- shared inner GEMM: NF frags starting at F0, kc-double-buffered B ----
template<int F0, int NF>
__device__ __forceinline__ void gemmHalf(const short* As, const short* bCol,
                                         int arow, int kg, f32x4* acc) {
    #pragma unroll
    for (int f = 0; f < NF; ++f) acc[f] = (f32x4){0.f, 0.f, 0.f, 0.f};
    bf16x8 bb[2][NF];
    #pragma unroll
    for (int f = 0; f < NF; ++f)
        bb[0][f] = *(const bf16x8*)(bCol + (size_t)(F0 + f) * 16 * KP);
    #pragma unroll
    for (int kc = 0; kc < 7; ++kc) {
        if (kc < 6) {
            #pragma unroll
            for (int f = 0; f < NF; ++f)
                bb[(kc + 1) & 1][f] = *(const bf16x8*)(bCol + (size_t)(F0 + f) * 16 * KP + (kc + 1) * 32);
        }
        bf16x8 a = *(const bf16x8*)(As + arow * AP + kc * 32 + kg);
        #pragma unroll
        for (int f = 0; f < NF; ++f)
            acc[f] = __builtin_amdgcn_mfma_f32_16x16x32_bf16(a, bb[kc & 1][f], acc[f], 0, 0, 0);
    }
}

// ---- y[i][:] = xb[i][:] @ root + bias ----
__global__ __launch_bounds__(256) void kRootGemm(const short* __restrict__ xb,
        const short* __restrict__ rootT, const float* __restrict__ bias,
        float* __restrict__ y) {
    __shared__ short As[TE * AP];
    int i0 = blockIdx.x * TE;
    int tid = threadIdx.x;
    int rowL = tid >> 2, sub = tid & 3;
    int i = i0 + rowL;
    for (int c = sub; c < 29; c += 4) {
        int4 v = make_int4(0, 0, 0, 0);
        if (i < NN && c < 26) v = *(const int4*)(xb + (size_t)i * XP + c * 8);
        *(int4*)(&As[rowL * AP + c * 8]) = v;
    }
    __syncthreads();
    int lane = tid & 63, wave = tid >> 6;
    int stripe = wave * 16;
    int arow = stripe + (lane & 15);
    int kg = (lane >> 4) * 8;
    const short* bCol = rootT + (lane & 15) * KP + kg;
    int colLane = lane & 15;
    int rbase = i0 + stripe + (lane >> 4) * 4;
    {
        f32x4 acc[7];
        gemmHalf<0, 7>(As, bCol, arow, kg, acc);
        #pragma unroll
        for (int f = 0; f < 7; ++f) {
            int col = f * 16 + colLane;
            float bv = bias[col];
            #pragma unroll
            for (int j = 0; j < 4; ++j) {
                int row = rbase + j;
                if (row < NN) y[(size_t)row * DD + col] = acc[f][j] + bv;
            }
        }
    }
    {
        f32x4 acc[6];
        gemmHalf<7, 6>(As, bCol, arow, kg, acc);
        #pragma unroll
        for (int f = 0; f < 6; ++f) {
            int col = (7 + f) * 16 + colLane;
            if (col < DD) {
                float bv = bias[col];
                #pragma unroll
                for (int j = 0; j < 4; ++j) {
                    int row = rbase + j;
                    if (row < NN) y[(size_t)row * DD + col] = acc[f][j] + bv;
                }
            }
        }
    }
}

// ---- per-(relation,tile) gather-GEMM; MODE 0: store msg rows; MODE 1: atomic y ----
template<int MODE>
__global__ __launch_bounds__(256) void kMsg(const int* __restrict__ ei,
        const short* __restrict__ xb, const short* __restrict__ Wt,
        const int* __restrict__ cnt, const int* __restrict__ sortedE,
        const float* __restrict__ norm, const int* __restrict__ posDst,
        float* __restrict__ y, short* __restrict__ msg) {
    __shared__ short As[TE * AP];
    __shared__ int   posS[TE];
    __shared__ float normS[TE];
    __shared__ int   dstS[TE];
    const int* tileOff  = cnt + 768;
    const int* relStart = cnt + 256;
    int bid = blockIdx.x;
    if (bid >= tileOff[RR]) return;
    int lo = 0, hi = RR;
    while (hi - lo > 1) {
        int mid = (lo + hi) >> 1;
        if (tileOff[mid] <= bid) lo = mid; else hi = mid;
    }
    int r = lo, tile = bid - tileOff[r];
    int eBase = relStart[r] + tile * TE;
    int eEnd  = relStart[r + 1];
    int tid = threadIdx.x;
    int rowL = tid >> 2, sub = tid & 3;
    int eIdx = eBase + rowL;
    bool valid = eIdx < eEnd;
    int eid = valid ? sortedE[eIdx] : 0;
    if (sub == 0) {
        normS[rowL] = valid ? norm[eid] : 0.0f;
        if (MODE == 0) posS[rowL] = valid ? posDst[eid] : -1;
        else           dstS[rowL] = valid ? ei[EE + eid] : 0;
    }
    int srcRow = valid ? ei[eid] : 0;
    for (int c = sub; c < 29; c += 4) {
        int4 v = make_int4(0, 0, 0, 0);
        if (valid && c < 26) v = *(const int4*)(xb + (size_t)srcRow * XP + c * 8);
        *(int4*)(&As[rowL * AP + c * 8]) = v;
    }
    __syncthreads();
    int lane = tid & 63, wave = tid >> 6;
    int stripe = wave * 16;
    int arow = stripe + (lane & 15);
    int kg = (lane >> 4) * 8;
    const short* bCol = Wt + (size_t)r * (NP * KP) + (lane & 15) * KP + kg;
    int colLane = lane & 15;
    int rL0 = stripe + (lane >> 4) * 4;
    {
        f32x4 acc[7];
        gemmHalf<0, 7>(As, bCol, arow, kg, acc);
        #pragma unroll
        for (int j = 0; j < 4; ++j) {
            int rl = rL0 + j;
            float nm = normS[rl];
            if (MODE == 0) {
                int pos = posS[rl];
                if (pos >= 0) {
                    #pragma unroll
                    for (int f = 0; f < 7; ++f) {
                        int col = f * 16 + colLane;
                        msg[(size_t)pos * MSGP + col] = f2bf(acc[f][j] * nm);
                    }
                }
            } else {
                if (nm != 0.0f) {
                    int dd = dstS[rl];
                    #pragma unroll
                    for (int f = 0; f < 7; ++f) {
                        int col = f * 16 + colLane;
                        atomicAdd(&y[(size_t)dd * DD + col], acc[f][j] * nm);
                    }
                }
            }
        }
    }
    {
        f32x4 acc[6];
        gemmHalf<7, 6>(As, bCol, arow, kg, acc);
        #pragma unroll
        for (int j = 0; j < 4; ++j) {
            int rl = rL0 + j;
            float nm = normS[rl];
            if (MODE == 0) {
                int pos = posS[rl];
                if (pos >= 0) {
                    #pragma unroll
                    for (int f = 0; f < 6; ++f) {
                        int col = (7 + f) * 16 + colLane;
                        if (col < DD) msg[(size_t)pos * MSGP + col] = f2bf(acc[f][j] * nm);
                    }
                }
            } else {
                if (nm != 0.0f) {
                    int dd = dstS[rl];
                    #pragma unroll
                    for (int f = 0; f < 6; ++f) {
                        int col = (7 + f) * 16 + colLane;
                        if (col < DD) atomicAdd(&y[(size_t)dd * DD + col], acc[f][j] * nm);
                    }
                }
            }
        }
    }
}

// ---- per-dst segmented sum of msg + root, relu; mode 0 -> xb (bf16), 1 -> y ----
__global__ __launch_bounds__(256) void kAgg(const short* __restrict__ msg,
        const int* __restrict__ dstStart, const float* __restrict__ yroot,
        float* __restrict__ yout, short* __restrict__ xbout, int mode) {
    int wv = threadIdx.x >> 6, lane = threadIdx.x & 63;
    int d = blockIdx.x * 4 + wv;
    if (d >= NN) return;
    int s = dstStart[d], e = dstStart[d + 1];
    float a0 = 0.f, a1 = 0.f, a2 = 0.f, a3 = 0.f;
    if (lane < 50) {
        for (int j = s; j < e; ++j) {
            int2 v = *(const int2*)(msg + (size_t)j * MSGP + lane * 4);
            unsigned u0 = (unsigned)v.x, u1 = (unsigned)v.y;
            a0 += __uint_as_float(u0 << 16);
            a1 += __uint_as_float(u0 & 0xffff0000u);
            a2 += __uint_as_float(u1 << 16);
            a3 += __uint_as_float(u1 & 0xffff0000u);
        }
    }
    int colBase = lane * 4;
    if (colBase < DD) {
        float4 rv = *(const float4*)(yroot + (size_t)d * DD + colBase);
        float o0 = fmaxf(rv.x + a0, 0.f);
        float o1 = fmaxf(rv.y + a1, 0.f);
        float o2 = fmaxf(rv.z + a2, 0.f);
        float o3 = fmaxf(rv.w + a3, 0.f);
        if (mode == 0) {
            int2 w;
            w.x = (int)pk2(o0, o1);
            w.y = (int)pk2(o2, o3);
            *(int2*)(xbout + (size_t)d * XP + colBase) = w;
        } else {
            *(float4*)(yout + (size_t)d * DD + colBase) = make_float4(o0, o1, o2, o3);
        }
    } else if (mode == 0 && colBase < XP) {
        *(int2*)(xbout + (size_t)d * XP + colBase) = make_int2(0, 0);
    }
}

extern "C" void kernel_launch(void* const* d_in, const int* in_sizes, int n_in,
                              void* d_out, int out_size, void* d_ws, size_t ws_size,
                              hipStream_t stream) {
    (void)in_sizes; (void)n_in; (void)out_size;
    const int*   ei    = (const int*)d_in[0];
    const int*   et    = (const int*)d_in[1];
    const float* emb   = (const float*)d_in[2];
    const float* comp  = (const float*)d_in[3];
    const float* bases = (const float*)d_in[4];
    const float* root  = (const float*)d_in[5];
    const float* bias  = (const float*)d_in[6];
    float* y = (float*)d_out;
    char* ws = (char*)d_ws;
    float* norm    = (float*)(ws + OFF_NORM);
    int*   sortedE = (int*)(ws + OFF_SORT);
    int*   cnt     = (int*)(ws + OFF_CNT);
    short* xb      = (short*)(ws + OFF_XB);
    short* Wt      = (short*)(ws + OFF_WT);
    short* rootT   = (short*)(ws + OFF_ROOTT);
    int*   posDst  = (int*)(ws + OFF_POS);
    int*   dstCnt  = (int*)(ws + OFF_DSTCNT);
    int*   dstStart= (int*)(ws + OFF_DSTST);
    int*   cur     = (int*)(ws + OFF_CUR);
    int*   blkSum  = (int*)(ws + OFF_BLK);
    short* msg     = (short*)(ws + OFF_MSG);
    unsigned int* deg8 = (unsigned int*)(ws + OFF_XB);  // transient alias

    int big = (ws_size >= WS_NEEDED) ? 1 : 0;
    const int NBLK = (NN + 255) / 256;  // 391

    hipMemsetAsync(deg8, 0, (size_t)NN * RR, stream);
    hipMemsetAsync(cnt, 0, 4096, stream);
    if (big) {
        hipMemsetAsync(dstCnt, 0, (size_t)NN * 4, stream);
        hipMemsetAsync(cur, 0, (size_t)NN * 4, stream);
    }
    kCount<<<(EE + 255) / 256, 256, 0, stream>>>(ei, et, deg8, cnt, dstCnt, big);
    kScan<<<1, 64, 0, stream>>>(cnt);
    if (big) {
        kScanBlk<<<NBLK, 256, 0, stream>>>(dstCnt, dstStart, blkSum);
        kScanTop<<<1, 512, 0, stream>>>(blkSum, NBLK);
        kScanAdd<<<NBLK, 256, 0, stream>>>(dstCnt, dstStart, blkSum);
    }
    kNormScatter<<<(EE + 255) / 256, 256, 0, stream>>>(ei, et, deg8, cnt, dstStart, cur,
                                                       norm, sortedE, posDst, big);
    kConvert<<<(NN * XP + 255) / 256, 256, 0, stream>>>(emb, xb, 0);

    for (int l = 0; l < LL; ++l) {
        kW<<<dim3(7, RR), 256, 0, stream>>>(comp + l * RR * BB,
                                            bases + (size_t)l * BB * DD * DD, Wt);
        kRootT<<<(NP * KP + 255) / 256, 256, 0, stream>>>(root + l * DD * DD, rootT);
        kRootGemm<<<(NN + TE - 1) / TE, 256, 0, stream>>>(xb, rootT, bias + l * DD, y);
        if (big) {
            kMsg<0><<<MAXTILES, 256, 0, stream>>>(ei, xb, Wt, cnt, sortedE, norm, posDst, y, msg);
            kAgg<<<(NN + 3) / 4, 256, 0, stream>>>(msg, dstStart, y, y, xb, (l == 0) ? 0 : 1);
        } else {
            kMsg<1><<<MAXTILES, 256, 0, stream>>>(ei, xb, Wt, cnt, sortedE, norm, posDst, y, msg);
            if (l == 0) kConvert<<<(NN * XP + 255) / 256, 256, 0, stream>>>(y, xb, 1);
            else        kRelu<<<(NN * DD + 255) / 256, 256, 0, stream>>>(y);
        }
    }
}

// Round 4
// 2109.947 us; speedup vs baseline: 1.6727x; 1.6727x over previous
//
#include <hip/hip_runtime.h>
#include <hip/hip_bf16.h>
#include <stdint.h>

// Problem constants
#define NN 100000   // nodes
#define RR 200      // relations
#define DD 200      // dim
#define BB 30       // bases
#define LL 2        // layers
#define EE 800000   // edges

// Padded GEMM geometry
#define KP 224      // K padded (7 x 32)
#define NP 208      // N padded (13 x 16)
#define XP 208      // xb row pitch (bf16)
#define AP 232      // LDS A-tile pitch (bf16)
#define TE 64       // edges per tile
#define MSGP 200    // msg row pitch (bf16) -> 400B
#define MAXTILES 12700
#define MAXNC 16

using bf16x8 = __attribute__((ext_vector_type(8))) short;
using f32x4  = __attribute__((ext_vector_type(4))) float;

// Workspace layout. Fallback path touches only < OFF_CTL.
#define OFF_NORM   0ull          // E f32
#define OFF_SORT   3200000ull    // E i32
#define OFF_CNT    6400000ull    // 4KB ctl (fallback)
#define OFF_XB     6404096ull    // N*XP bf16 (deg8 20MB aliases transiently)
#define OFF_WT     48004096ull   // R*NP*KP bf16
#define OFF_ROOTT  66640896ull   // NP*KP bf16
#define OFF_CTL    66734080ull   // 64KB ctl (big)
#define OFF_POS    66799616ull   // E i32
#define OFF_DSTCNT 69999616ull   // N i32
#define OFF_DSTST  70399616ull   // (N+1) i32 (+pad)
#define OFF_CUR    70799632ull   // N i32
#define OFF_MSG    71199632ull   // chunk msg buffer, (T+64)*MSGP*2 bytes

static __device__ __forceinline__ short f2bf(float v) {
    union { __hip_bfloat16 h; short s; } u;
    u.h = __float2bfloat16(v);
    return u.s;
}

// ---- deg per (dst,rel) + per-dst histogram ----
__global__ void kCount(const int* __restrict__ ei, const int* __restrict__ et,
                       unsigned int* __restrict__ deg8, int* __restrict__ dstCnt, int big) {
    int e = blockIdx.x * 256 + threadIdx.x;
    if (e >= EE) return;
    int d = ei[EE + e];
    int t = et[e];
    int comb = d * RR + t;
    atomicAdd(&deg8[comb >> 2], 1u << ((comb & 3) * 8));
    if (big) atomicAdd(&dstCnt[d], 1);
}

// ---- 3-kernel exclusive scan of dstCnt[N] -> dstStart[N+1] ----
__global__ void kScanBlk(const int* __restrict__ dstCnt, int* __restrict__ dstStart,
                         int* __restrict__ blkSum) {
    __shared__ int s[256];
    int t = threadIdx.x, i = blockIdx.x * 256 + t;
    int v = (i < NN) ? dstCnt[i] : 0;
    s[t] = v;
    __syncthreads();
    #pragma unroll
    for (int off = 1; off < 256; off <<= 1) {
        int x = (t >= off) ? s[t - off] : 0;
        __syncthreads();
        s[t] += x;
        __syncthreads();
    }
    if (i < NN) dstStart[i] = s[t] - v;
    if (t == 255) blkSum[blockIdx.x] = s[255];
}
__global__ void kScanTop(int* __restrict__ blkSum, int nblk) {
    __shared__ int s[512];
    int t = threadIdx.x;
    int v = (t < nblk) ? blkSum[t] : 0;
    s[t] = v;
    __syncthreads();
    #pragma unroll
    for (int off = 1; off < 512; off <<= 1) {
        int x = (t >= off) ? s[t - off] : 0;
        __syncthreads();
        s[t] += x;
        __syncthreads();
    }
    if (t < nblk) blkSum[t] = s[t] - v;
}
__global__ void kScanAdd(const int* __restrict__ dstCnt, int* __restrict__ dstStart,
                         const int* __restrict__ blkSum) {
    int i = blockIdx.x * 256 + threadIdx.x;
    if (i >= NN) return;
    int v = dstStart[i] + blkSum[blockIdx.x];
    dstStart[i] = v;
    if (i == NN - 1) dstStart[NN] = v + dstCnt[i];
}

// ---- chunk boundaries: b[c] = smallest node with dstStart >= c*T ----
__global__ void kChunk(const int* __restrict__ dstStart, int* __restrict__ bS,
                       int* __restrict__ cesS, int NC, int T) {
    int tid = threadIdx.x;
    if (tid > NC) return;
    int v;
    if (tid == NC) v = NN;
    else if (tid == 0) v = 0;
    else {
        int target = tid * T;
        int lo = 0, hi = NN;
        while (lo < hi) {
            int mid = (lo + hi) >> 1;
            if (dstStart[mid] >= target) hi = mid; else lo = mid + 1;
        }
        v = lo;
    }
    bS[tid] = v;
    cesS[tid] = dstStart[v];
}

// ---- (chunk, rel) bucket histogram ----
__global__ void kCountB(const int* __restrict__ ei, const int* __restrict__ et,
                        const int* __restrict__ bS, int* __restrict__ cntB, int NC) {
    __shared__ int bsh[MAXNC + 1];
    if (threadIdx.x <= NC) bsh[threadIdx.x] = bS[threadIdx.x];
    __syncthreads();
    int e = blockIdx.x * 256 + threadIdx.x;
    if (e >= EE) return;
    int d = ei[EE + e];
    int t = et[e];
    int c = 0;
    for (int j = 1; j < NC; ++j) if (d >= bsh[j]) c = j;
    atomicAdd(&cntB[c * RR + t], 1);
}

// ---- bucket scan (nb <= 3200) ----
__global__ void kScanB(const int* __restrict__ cntB, int* __restrict__ relStartB,
                       int* __restrict__ cursorB, int* __restrict__ tileOffB, int nb) {
    __shared__ int c[MAXNC * RR];
    __shared__ int rs[MAXNC * RR + 1];
    __shared__ int to[MAXNC * RR + 1];
    int tid = threadIdx.x;
    for (int i = tid; i < nb; i += 256) c[i] = cntB[i];
    __syncthreads();
    if (tid == 0) {
        int s = 0, ts = 0;
        for (int i = 0; i < nb; ++i) {
            rs[i] = s; to[i] = ts;
            s += c[i];
            ts += (c[i] + TE - 1) / TE;
        }
        rs[nb] = s; to[nb] = ts;
    }
    __syncthreads();
    for (int i = tid; i <= nb; i += 256) {
        relStartB[i] = rs[i];
        tileOffB[i]  = to[i];
        if (i < nb) cursorB[i] = rs[i];
    }
}

// ---- per-edge norm + counting-sort by bucket + dst-slot ----
__global__ void kNormScatter(const int* __restrict__ ei, const int* __restrict__ et,
                             const unsigned int* __restrict__ deg8, const int* __restrict__ bS,
                             int* __restrict__ cursorB, const int* __restrict__ dstStart,
                             int* __restrict__ cur, float* __restrict__ norm,
                             int* __restrict__ sortedE, int* __restrict__ posDst,
                             int NC, int big) {
    __shared__ int bsh[MAXNC + 1];
    if (threadIdx.x <= NC) bsh[threadIdx.x] = bS[threadIdx.x];
    __syncthreads();
    int e = blockIdx.x * 256 + threadIdx.x;
    if (e >= EE) return;
    int d = ei[EE + e];
    int t = et[e];
    int comb = d * RR + t;
    unsigned int deg = (deg8[comb >> 2] >> ((comb & 3) * 8)) & 0xffu;
    norm[e] = 1.0f / (float)(deg ? deg : 1u);
    int c = 0;
    for (int j = 1; j < NC; ++j) if (d >= bsh[j]) c = j;
    int pos = atomicAdd(&cursorB[c * RR + t], 1);
    sortedE[pos] = e;
    if (big) posDst[e] = dstStart[d] + atomicAdd(&cur[d], 1);
}

// ---- fp32 [N,DD] -> bf16 [N,XP] ----
__global__ void kConvert(const float* __restrict__ x, short* __restrict__ xb, int doRelu) {
    int idx = blockIdx.x * 256 + threadIdx.x;
    if (idx >= NN * XP) return;
    int i = idx / XP, col = idx - i * XP;
    float v = 0.0f;
    if (col < DD) {
        v = x[i * DD + col];
        if (doRelu) v = fmaxf(v, 0.0f);
    }
    xb[idx] = (col < DD) ? f2bf(v) : (short)0;
}

__global__ void kRelu(float* __restrict__ y) {
    int idx = blockIdx.x * 256 + threadIdx.x;
    if (idx < NN * DD) y[idx] = fmaxf(y[idx], 0.0f);
}

// ---- Wt[r][n][k] = sum_b comp[r][b]*bases[b][k][n]; load-once-per-cell ----
__global__ __launch_bounds__(256) void kW(const float* __restrict__ comp,
                                          const float* __restrict__ bases,
                                          short* __restrict__ Wt) {
    int kt = blockIdx.x;                  // 0..6
    int ng = blockIdx.y;                  // 0..25
    int tid = threadIdx.x;
    int k = kt * 32 + (tid & 31);
    int n = ng * 8 + (tid >> 5);
    bool live = (k < DD) && (n < DD);
    float vb[BB];
    #pragma unroll
    for (int b = 0; b < BB; ++b)
        vb[b] = live ? bases[((size_t)b * DD + k) * DD + n] : 0.0f;
    size_t wo = (size_t)n * KP + k;
    for (int r = 0; r < RR; ++r) {
        float a = 0.0f;
        #pragma unroll
        for (int b = 0; b < BB; ++b) a += comp[r * BB + b] * vb[b];
        Wt[(size_t)r * (NP * KP) + wo] = f2bf(a);
    }
}

// ---- rootT[n][k] = root[k][n] ----
__global__ void kRootT(const float* __restrict__ root, short* __restrict__ rootT) {
    int idx = blockIdx.x * 256 + threadIdx.x;
    if (idx >= NP * KP) return;
    int n = idx / KP, k = idx - n * KP;
    rootT[idx] = (n < DD && k < DD) ? f2bf(root[k * DD + n]) : (short)0;
}

// ---- shared inner GEMM: NF frags from F0, kc-double-buffered B ----
template<int F0, int NF>
__device__ __forceinline__ void gemmHalf(const short* As, const short* bCol,
                                         int arow, int kg, f32x4* acc) {
    #pragma unroll
    for (int f = 0; f < NF; ++f) acc[f] = (f32x4){0.f, 0.f, 0.f, 0.f};
    bf16x8 bb[2][NF];
    #pragma unroll
    for (int f = 0; f < NF; ++f)
        bb[0][f] = *(const bf16x8*)(bCol + (size_t)(F0 + f) * 16 * KP);
    #pragma unroll
    for (int kc = 0; kc < 7; ++kc) {
        if (kc < 6) {
            #pragma unroll
            for (int f = 0; f < NF; ++f)
                bb[(kc + 1) & 1][f] = *(const bf16x8*)(bCol + (size_t)(F0 + f) * 16 * KP + (kc + 1) * 32);
        }
        bf16x8 a = *(const bf16x8*)(As + arow * AP + kc * 32 + kg);
        #pragma unroll
        for (int f = 0; f < NF; ++f)
            acc[f] = __builtin_amdgcn_mfma_f32_16x16x32_bf16(a, bb[kc & 1][f], acc[f], 0, 0, 0);
    }
}

// ---- y[i][:] = xb[i][:] @ root + bias ----
__global__ __launch_bounds__(256) void kRootGemm(const short* __restrict__ xb,
        const short* __restrict__ rootT, const float* __restrict__ bias,
        float* __restrict__ y) {
    __shared__ short As[TE * AP];
    int i0 = blockIdx.x * TE;
    int tid = threadIdx.x;
    int rowL = tid >> 2, sub = tid & 3;
    int i = i0 + rowL;
    for (int c = sub; c < 29; c += 4) {
        int4 v = make_int4(0, 0, 0, 0);
        if (i < NN && c < 26) v = *(const int4*)(xb + (size_t)i * XP + c * 8);
        *(int4*)(&As[rowL * AP + c * 8]) = v;
    }
    __syncthreads();
    int lane = tid & 63, wave = tid >> 6;
    int stripe = wave * 16;
    int arow = stripe + (lane & 15);
    int kg = (lane >> 4) * 8;
    const short* bCol = rootT + (lane & 15) * KP + kg;
    int colLane = lane & 15;
    int rbase = i0 + stripe + (lane >> 4) * 4;
    {
        f32x4 acc[7];
        gemmHalf<0, 7>(As, bCol, arow, kg, acc);
        #pragma unroll
        for (int f = 0; f < 7; ++f) {
            int col = f * 16 + colLane;
            float bv = bias[col];
            #pragma unroll
            for (int j = 0; j < 4; ++j) {
                int row = rbase + j;
                if (row < NN) y[(size_t)row * DD + col] = acc[f][j] + bv;
            }
        }
    }
    {
        f32x4 acc[6];
        gemmHalf<7, 6>(As, bCol, arow, kg, acc);
        #pragma unroll
        for (int f = 0; f < 6; ++f) {
            int col = (7 + f) * 16 + colLane;
            if (col < DD) {
                float bv = bias[col];
                #pragma unroll
                for (int j = 0; j < 4; ++j) {
                    int row = rbase + j;
                    if (row < NN) y[(size_t)row * DD + col] = acc[f][j] + bv;
                }
            }
        }
    }
}

// ---- per-(bucket,tile) gather-GEMM; MODE 0: store msg rows; MODE 1: atomic y ----
template<int MODE>
__global__ __launch_bounds__(256) void kMsg(const int* __restrict__ ei,
        const short* __restrict__ xb, const short* __restrict__ Wt,
        const int* __restrict__ relStartB, const int* __restrict__ tileOffB,
        const int* __restrict__ sortedE, const float* __restrict__ norm,
        const int* __restrict__ posDst, const int* __restrict__ cesS,
        float* __restrict__ y, short* __restrict__ msg, int c) {
    __shared__ short As[TE * AP];
    __shared__ int   posS[TE];
    __shared__ float normS[TE];
    int tbase = tileOffB[c * RR];
    int tend  = tileOffB[(c + 1) * RR];
    int tileIdx = tbase + blockIdx.x;
    if (tileIdx >= tend) return;
    int lo = c * RR, hi = (c + 1) * RR;
    while (hi - lo > 1) {
        int mid = (lo + hi) >> 1;
        if (tileOffB[mid] <= tileIdx) lo = mid; else hi = mid;
    }
    int bkt = lo;
    int r = bkt - c * RR;
    int eBase = relStartB[bkt] + (tileIdx - tileOffB[bkt]) * TE;
    int eEnd  = relStartB[bkt + 1];
    int tid = threadIdx.x;
    int rowL = tid >> 2, sub = tid & 3;
    int eIdx = eBase + rowL;
    bool valid = eIdx < eEnd;
    int eid = valid ? sortedE[eIdx] : 0;
    if (sub == 0) {
        normS[rowL] = valid ? norm[eid] : 0.0f;
        if (MODE == 0) posS[rowL] = valid ? (posDst[eid] - cesS[c]) : -1;
        else           posS[rowL] = valid ? ei[EE + eid] : -1;
    }
    int srcRow = valid ? ei[eid] : 0;
    for (int cc = sub; cc < 29; cc += 4) {
        int4 v = make_int4(0, 0, 0, 0);
        if (valid && cc < 26) v = *(const int4*)(xb + (size_t)srcRow * XP + cc * 8);
        *(int4*)(&As[rowL * AP + cc * 8]) = v;
    }
    __syncthreads();
    int lane = tid & 63, wave = tid >> 6;
    int stripe = wave * 16;
    int arow = stripe + (lane & 15);
    int kg = (lane >> 4) * 8;
    const short* bCol = Wt + (size_t)r * (NP * KP) + (lane & 15) * KP + kg;
    int colLane = lane & 15;
    int rL0 = stripe + (lane >> 4) * 4;
    {
        f32x4 acc[7];
        gemmHalf<0, 7>(As, bCol, arow, kg, acc);
        #pragma unroll
        for (int j = 0; j < 4; ++j) {
            int rl = rL0 + j;
            float nm = normS[rl];
            int ps = posS[rl];
            if (ps >= 0) {
                #pragma unroll
                for (int f = 0; f < 7; ++f) {
                    int col = f * 16 + colLane;
                    if (MODE == 0) msg[(size_t)ps * MSGP + col] = f2bf(acc[f][j] * nm);
                    else           atomicAdd(&y[(size_t)ps * DD + col], acc[f][j] * nm);
                }
            }
        }
    }
    {
        f32x4 acc[6];
        gemmHalf<7, 6>(As, bCol, arow, kg, acc);
        #pragma unroll
        for (int j = 0; j < 4; ++j) {
            int rl = rL0 + j;
            float nm = normS[rl];
            int ps = posS[rl];
            if (ps >= 0) {
                #pragma unroll
                for (int f = 0; f < 6; ++f) {
                    int col = (7 + f) * 16 + colLane;
                    if (col < DD) {
                        if (MODE == 0) msg[(size_t)ps * MSGP + col] = f2bf(acc[f][j] * nm);
                        else           atomicAdd(&y[(size_t)ps * DD + col], acc[f][j] * nm);
                    }
                }
            }
        }
    }
}

// ---- grid-stride segmented sum over chunk's node range; y = relu(y + sum(msg)) ----
__global__ __launch_bounds__(256) void kAgg(const short* __restrict__ msg,
        const int* __restrict__ dstStart, const int* __restrict__ bS,
        const int* __restrict__ cesS, float* __restrict__ y, int c) {
    int wv = threadIdx.x >> 6, lane = threadIdx.x & 63;
    int b0 = bS[c], b1 = bS[c + 1];
    int ces = cesS[c];
    int gw = blockIdx.x * 4 + wv;
    int nw = gridDim.x * 4;
    for (int d = b0 + gw; d < b1; d += nw) {
        int s = dstStart[d] - ces, e = dstStart[d + 1] - ces;
        float a0 = 0.f, a1 = 0.f, a2 = 0.f, a3 = 0.f;
        if (lane < 50) {
            for (int j = s; j < e; ++j) {
                int2 v = *(const int2*)(msg + (size_t)j * MSGP + lane * 4);
                unsigned u0 = (unsigned)v.x, u1 = (unsigned)v.y;
                a0 += __uint_as_float(u0 << 16);
                a1 += __uint_as_float(u0 & 0xffff0000u);
                a2 += __uint_as_float(u1 << 16);
                a3 += __uint_as_float(u1 & 0xffff0000u);
            }
            int colBase = lane * 4;
            float4 rv = *(const float4*)(y + (size_t)d * DD + colBase);
            float4 o;
            o.x = fmaxf(rv.x + a0, 0.f);
            o.y = fmaxf(rv.y + a1, 0.f);
            o.z = fmaxf(rv.z + a2, 0.f);
            o.w = fmaxf(rv.w + a3, 0.f);
            *(float4*)(y + (size_t)d * DD + colBase) = o;
        }
    }
}

extern "C" void kernel_launch(void* const* d_in, const int* in_sizes, int n_in,
                              void* d_out, int out_size, void* d_ws, size_t ws_size,
                              hipStream_t stream) {
    (void)in_sizes; (void)n_in; (void)out_size;
    const int*   ei    = (const int*)d_in[0];
    const int*   et    = (const int*)d_in[1];
    const float* emb   = (const float*)d_in[2];
    const float* comp  = (const float*)d_in[3];
    const float* bases = (const float*)d_in[4];
    const float* root  = (const float*)d_in[5];
    const float* bias  = (const float*)d_in[6];
    float* y = (float*)d_out;
    char* ws = (char*)d_ws;
    float* norm    = (float*)(ws + OFF_NORM);
    int*   sortedE = (int*)(ws + OFF_SORT);
    short* xb      = (short*)(ws + OFF_XB);
    short* Wt      = (short*)(ws + OFF_WT);
    short* rootT   = (short*)(ws + OFF_ROOTT);
    int*   posDst  = (int*)(ws + OFF_POS);
    int*   dstCnt  = (int*)(ws + OFF_DSTCNT);
    int*   dstStart= (int*)(ws + OFF_DSTST);
    int*   cur     = (int*)(ws + OFF_CUR);
    short* msg     = (short*)(ws + OFF_MSG);
    unsigned int* deg8 = (unsigned int*)(ws + OFF_XB);  // transient alias

    // choose chunk count from available workspace (pure function of ws_size)
    int NC = 0;
    long long T = EE;
    for (int cc = 1; cc <= MAXNC; ++cc) {
        long long t = (EE + cc - 1) / cc;
        if ((unsigned long long)ws_size >= OFF_MSG + (unsigned long long)(t + 64) * (MSGP * 2)) {
            NC = cc; T = t; break;
        }
    }
    int big = (NC > 0) ? 1 : 0;
    if (!big) { NC = 1; T = EE; }

    int *cntB, *relStartB, *cursorB, *tileOffB, *bS, *cesS, *blkSum;
    if (big) {
        int* ctl = (int*)(ws + OFF_CTL);
        cntB = ctl; relStartB = ctl + 3328; cursorB = ctl + 6656;
        tileOffB = ctl + 9984; bS = ctl + 13312; cesS = ctl + 13360; blkSum = ctl + 13440;
    } else {
        int* ctl = (int*)(ws + OFF_CNT);
        cntB = ctl; relStartB = ctl + 256; cursorB = ctl + 512;
        tileOffB = ctl + 768; bS = ctl + 976; cesS = ctl + 992; blkSum = ctl + 1000;
    }

    const int NBLK = (NN + 255) / 256;  // 391

    hipMemsetAsync(deg8, 0, (size_t)NN * RR, stream);
    if (big) {
        hipMemsetAsync((void*)cntB, 0, 65536, stream);
        hipMemsetAsync(dstCnt, 0, (size_t)NN * 4, stream);
        hipMemsetAsync(cur, 0, (size_t)NN * 4, stream);
    } else {
        hipMemsetAsync((void*)cntB, 0, 4096, stream);
    }

    kCount<<<(EE + 255) / 256, 256, 0, stream>>>(ei, et, deg8, dstCnt, big);
    if (big) {
        kScanBlk<<<NBLK, 256, 0, stream>>>(dstCnt, dstStart, blkSum);
        kScanTop<<<1, 512, 0, stream>>>(blkSum, NBLK);
        kScanAdd<<<NBLK, 256, 0, stream>>>(dstCnt, dstStart, blkSum);
        kChunk<<<1, 64, 0, stream>>>(dstStart, bS, cesS, NC, (int)T);
    }
    kCountB<<<(EE + 255) / 256, 256, 0, stream>>>(ei, et, bS, cntB, NC);
    kScanB<<<1, 256, 0, stream>>>(cntB, relStartB, cursorB, tileOffB, NC * RR);
    kNormScatter<<<(EE + 255) / 256, 256, 0, stream>>>(ei, et, deg8, bS, cursorB,
                                                       dstStart, cur, norm, sortedE,
                                                       posDst, NC, big);
    kConvert<<<(NN * XP + 255) / 256, 256, 0, stream>>>(emb, xb, 0);

    int Gmsg = (int)((T + 64 + 63) / 64) + RR + 4;
    for (int l = 0; l < LL; ++l) {
        kW<<<dim3(7, 26), 256, 0, stream>>>(comp + l * RR * BB,
                                            bases + (size_t)l * BB * DD * DD, Wt);
        kRootT<<<(NP * KP + 255) / 256, 256, 0, stream>>>(root + l * DD * DD, rootT);
        kRootGemm<<<(NN + TE - 1) / TE, 256, 0, stream>>>(xb, rootT, bias + l * DD, y);
        if (big) {
            for (int c = 0; c < NC; ++c) {
                kMsg<0><<<Gmsg, 256, 0, stream>>>(ei, xb, Wt, relStartB, tileOffB,
                                                  sortedE, norm, posDst, cesS, y, msg, c);
                kAgg<<<2048, 256, 0, stream>>>(msg, dstStart, bS, cesS, y, c);
            }
            if (l == 0)
                kConvert<<<(NN * XP + 255) / 256, 256, 0, stream>>>(y, xb, 0);
        } else {
            kMsg<1><<<MAXTILES, 256, 0, stream>>>(ei, xb, Wt, relStartB, tileOffB,
                                                  sortedE, norm, posDst, cesS, y, msg, 0);
            if (l == 0) kConvert<<<(NN * XP + 255) / 256, 256, 0, stream>>>(y, xb, 1);
            else        kRelu<<<(NN * DD + 255) / 256, 256, 0, stream>>>(y);
        }
    }
}

// Round 5
// 1579.650 us; speedup vs baseline: 2.2342x; 1.3357x over previous
//
#include <hip/hip_runtime.h>
#include <hip/hip_bf16.h>
#include <stdint.h>

// Problem constants
#define NN 100000   // nodes
#define RR 200      // relations
#define DD 200      // dim
#define BB 30       // bases
#define LL 2        // layers
#define EE 800000   // edges

// Padded GEMM geometry
#define KP 224      // K padded (7 x 32)
#define NP 208      // N padded (13 x 16)
#define XP 208      // xb row pitch (bf16)
#define AP 232      // LDS A-tile pitch (bf16)
#define TE 64       // edges per tile
#define MSGP 200    // msg row pitch (bf16) -> 400B
#define MAXTILES 12700
#define MAXNC 16
#define NPART 256   // partition blocks for the 2-pass sort
#define EPB ((EE + NPART - 1) / NPART)   // 3125 edges per partition

using bf16x8 = __attribute__((ext_vector_type(8))) short;
using f32x4  = __attribute__((ext_vector_type(4))) float;

// Workspace layout. Fallback path touches only < OFF_CTL.
#define OFF_NORM   0ull          // E f32
#define OFF_SORT   3200000ull    // E i32
#define OFF_CNT    6400000ull    // 4KB ctl (fallback)
#define OFF_XB     6404096ull    // N*XP bf16 (deg8 20MB aliases transiently)
#define OFF_WT     48004096ull   // R*NP*KP bf16
#define OFF_ROOTT  66640896ull   // NP*KP bf16
#define OFF_CTL    66734080ull   // 64KB ctl (big)
#define OFF_POS    66799616ull   // E i32
#define OFF_DSTCNT 69999616ull   // N i32
#define OFF_DSTST  70399616ull   // (N+1) i32 (+pad)
#define OFF_CUR    70799632ull   // N i32
#define OFF_BLKH   71199632ull   // NPART * MAXNC*RR i32 = 3,276,800
#define OFF_MSG    74476432ull   // chunk msg buffer, (T+64)*MSGP*2 bytes

static __device__ __forceinline__ short f2bf(float v) {
    union { __hip_bfloat16 h; short s; } u;
    u.h = __float2bfloat16(v);
    return u.s;
}

// ---- deg per (dst,rel) + per-dst histogram ----
__global__ void kCount(const int* __restrict__ ei, const int* __restrict__ et,
                       unsigned int* __restrict__ deg8, int* __restrict__ dstCnt, int big) {
    int e = blockIdx.x * 256 + threadIdx.x;
    if (e >= EE) return;
    int d = ei[EE + e];
    int t = et[e];
    int comb = d * RR + t;
    atomicAdd(&deg8[comb >> 2], 1u << ((comb & 3) * 8));
    if (big) atomicAdd(&dstCnt[d], 1);
}

// ---- 3-kernel exclusive scan of dstCnt[N] -> dstStart[N+1] ----
__global__ void kScanBlk(const int* __restrict__ dstCnt, int* __restrict__ dstStart,
                         int* __restrict__ blkSum) {
    __shared__ int s[256];
    int t = threadIdx.x, i = blockIdx.x * 256 + t;
    int v = (i < NN) ? dstCnt[i] : 0;
    s[t] = v;
    __syncthreads();
    #pragma unroll
    for (int off = 1; off < 256; off <<= 1) {
        int x = (t >= off) ? s[t - off] : 0;
        __syncthreads();
        s[t] += x;
        __syncthreads();
    }
    if (i < NN) dstStart[i] = s[t] - v;
    if (t == 255) blkSum[blockIdx.x] = s[255];
}
__global__ void kScanTop(int* __restrict__ blkSum, int nblk) {
    __shared__ int s[512];
    int t = threadIdx.x;
    int v = (t < nblk) ? blkSum[t] : 0;
    s[t] = v;
    __syncthreads();
    #pragma unroll
    for (int off = 1; off < 512; off <<= 1) {
        int x = (t >= off) ? s[t - off] : 0;
        __syncthreads();
        s[t] += x;
        __syncthreads();
    }
    if (t < nblk) blkSum[t] = s[t] - v;
}
__global__ void kScanAdd(const int* __restrict__ dstCnt, int* __restrict__ dstStart,
                         const int* __restrict__ blkSum) {
    int i = blockIdx.x * 256 + threadIdx.x;
    if (i >= NN) return;
    int v = dstStart[i] + blkSum[blockIdx.x];
    dstStart[i] = v;
    if (i == NN - 1) dstStart[NN] = v + dstCnt[i];
}

// ---- chunk boundaries: b[c] = smallest node with dstStart >= c*T ----
__global__ void kChunk(const int* __restrict__ dstStart, int* __restrict__ bS,
                       int* __restrict__ cesS, int NC, int T) {
    int tid = threadIdx.x;
    if (tid > NC) return;
    int v;
    if (tid == NC) v = NN;
    else if (tid == 0) v = 0;
    else {
        int target = tid * T;
        int lo = 0, hi = NN;
        while (lo < hi) {
            int mid = (lo + hi) >> 1;
            if (dstStart[mid] >= target) hi = mid; else lo = mid + 1;
        }
        v = lo;
    }
    bS[tid] = v;
    cesS[tid] = dstStart[v];
}

// ---- PASS 1: per-partition LDS histogram of (chunk,rel) buckets ----
__global__ __launch_bounds__(256) void kHist(const int* __restrict__ ei,
        const int* __restrict__ et, const int* __restrict__ bS,
        int* __restrict__ blockHist, int NC) {
    __shared__ int hist[MAXNC * RR];
    __shared__ int bsh[MAXNC + 1];
    int tid = threadIdx.x, b = blockIdx.x;
    int NB = NC * RR;
    if (tid <= NC) bsh[tid] = bS[tid];
    for (int i = tid; i < NB; i += 256) hist[i] = 0;
    __syncthreads();
    int ebeg = b * EPB, eend = min(EE, ebeg + EPB);
    for (int e = ebeg + tid; e < eend; e += 256) {
        int d = ei[EE + e];
        int t = et[e];
        int c = 0;
        for (int j = 1; j < NC; ++j) if (d >= bsh[j]) c = j;
        atomicAdd(&hist[c * RR + t], 1);
    }
    __syncthreads();
    for (int i = tid; i < NB; i += 256)
        blockHist[(size_t)b * NB + i] = hist[i];
}

// ---- PASS 1b: per-bucket exclusive scan across partitions; totals -> cntB ----
__global__ __launch_bounds__(256) void kScanP(int* __restrict__ blockHist,
                                              int* __restrict__ cntB, int NB) {
    __shared__ int s[256];
    int t = threadIdx.x, k = blockIdx.x;
    int v = blockHist[(size_t)t * NB + k];
    s[t] = v;
    __syncthreads();
    #pragma unroll
    for (int off = 1; off < 256; off <<= 1) {
        int x = (t >= off) ? s[t - off] : 0;
        __syncthreads();
        s[t] += x;
        __syncthreads();
    }
    blockHist[(size_t)t * NB + k] = s[t] - v;
    if (t == 255) cntB[k] = s[255];
}

// ---- bucket scan (nb <= 3200) ----
__global__ void kScanB(const int* __restrict__ cntB, int* __restrict__ relStartB,
                       int* __restrict__ cursorB, int* __restrict__ tileOffB, int nb) {
    __shared__ int c[MAXNC * RR];
    __shared__ int rs[MAXNC * RR + 1];
    __shared__ int to[MAXNC * RR + 1];
    int tid = threadIdx.x;
    for (int i = tid; i < nb; i += 256) c[i] = cntB[i];
    __syncthreads();
    if (tid == 0) {
        int s = 0, ts = 0;
        for (int i = 0; i < nb; ++i) {
            rs[i] = s; to[i] = ts;
            s += c[i];
            ts += (c[i] + TE - 1) / TE;
        }
        rs[nb] = s; to[nb] = ts;
    }
    __syncthreads();
    for (int i = tid; i <= nb; i += 256) {
        relStartB[i] = rs[i];
        tileOffB[i]  = to[i];
        if (i < nb) cursorB[i] = rs[i];
    }
}

// ---- PASS 2: partition scatter with LDS cursors; norm + posDst fused ----
__global__ __launch_bounds__(256) void kPart(const int* __restrict__ ei,
        const int* __restrict__ et, const unsigned int* __restrict__ deg8,
        const int* __restrict__ bS, const int* __restrict__ relStartB,
        const int* __restrict__ blockHist, const int* __restrict__ dstStart,
        int* __restrict__ cur, float* __restrict__ norm, int* __restrict__ sortedE,
        int* __restrict__ posDst, int NC) {
    __shared__ int curL[MAXNC * RR];
    __shared__ int bsh[MAXNC + 1];
    int tid = threadIdx.x, b = blockIdx.x;
    int NB = NC * RR;
    if (tid <= NC) bsh[tid] = bS[tid];
    for (int i = tid; i < NB; i += 256)
        curL[i] = relStartB[i] + blockHist[(size_t)b * NB + i];
    __syncthreads();
    int ebeg = b * EPB, eend = min(EE, ebeg + EPB);
    for (int e = ebeg + tid; e < eend; e += 256) {
        int d = ei[EE + e];
        int t = et[e];
        int comb = d * RR + t;
        unsigned int deg = (deg8[comb >> 2] >> ((comb & 3) * 8)) & 0xffu;
        norm[e] = 1.0f / (float)(deg ? deg : 1u);
        int c = 0;
        for (int j = 1; j < NC; ++j) if (d >= bsh[j]) c = j;
        int pos = atomicAdd(&curL[c * RR + t], 1);
        sortedE[pos] = e;
        posDst[e] = dstStart[d] + atomicAdd(&cur[d], 1);
    }
}

// ---- fallback-only: (chunk, rel) bucket histogram via global atomics ----
__global__ void kCountB(const int* __restrict__ ei, const int* __restrict__ et,
                        const int* __restrict__ bS, int* __restrict__ cntB, int NC) {
    __shared__ int bsh[MAXNC + 1];
    if (threadIdx.x <= NC) bsh[threadIdx.x] = bS[threadIdx.x];
    __syncthreads();
    int e = blockIdx.x * 256 + threadIdx.x;
    if (e >= EE) return;
    int d = ei[EE + e];
    int t = et[e];
    int c = 0;
    for (int j = 1; j < NC; ++j) if (d >= bsh[j]) c = j;
    atomicAdd(&cntB[c * RR + t], 1);
}

// ---- fallback-only: per-edge norm + counting-sort via global cursors ----
__global__ void kNormScatter(const int* __restrict__ ei, const int* __restrict__ et,
                             const unsigned int* __restrict__ deg8, const int* __restrict__ bS,
                             int* __restrict__ cursorB, const int* __restrict__ dstStart,
                             int* __restrict__ cur, float* __restrict__ norm,
                             int* __restrict__ sortedE, int* __restrict__ posDst,
                             int NC, int big) {
    __shared__ int bsh[MAXNC + 1];
    if (threadIdx.x <= NC) bsh[threadIdx.x] = bS[threadIdx.x];
    __syncthreads();
    int e = blockIdx.x * 256 + threadIdx.x;
    if (e >= EE) return;
    int d = ei[EE + e];
    int t = et[e];
    int comb = d * RR + t;
    unsigned int deg = (deg8[comb >> 2] >> ((comb & 3) * 8)) & 0xffu;
    norm[e] = 1.0f / (float)(deg ? deg : 1u);
    int c = 0;
    for (int j = 1; j < NC; ++j) if (d >= bsh[j]) c = j;
    int pos = atomicAdd(&cursorB[c * RR + t], 1);
    sortedE[pos] = e;
    if (big) posDst[e] = dstStart[d] + atomicAdd(&cur[d], 1);
}

// ---- fp32 [N,DD] -> bf16 [N,XP] ----
__global__ void kConvert(const float* __restrict__ x, short* __restrict__ xb, int doRelu) {
    int idx = blockIdx.x * 256 + threadIdx.x;
    if (idx >= NN * XP) return;
    int i = idx / XP, col = idx - i * XP;
    float v = 0.0f;
    if (col < DD) {
        v = x[i * DD + col];
        if (doRelu) v = fmaxf(v, 0.0f);
    }
    xb[idx] = (col < DD) ? f2bf(v) : (short)0;
}

__global__ void kRelu(float* __restrict__ y) {
    int idx = blockIdx.x * 256 + threadIdx.x;
    if (idx < NN * DD) y[idx] = fmaxf(y[idx], 0.0f);
}

// ---- Wt[r][n][k] = sum_b comp[r][b]*bases[b][k][n]; load-once-per-cell ----
__global__ __launch_bounds__(256) void kW(const float* __restrict__ comp,
                                          const float* __restrict__ bases,
                                          short* __restrict__ Wt) {
    int kt = blockIdx.x;                  // 0..6
    int ng = blockIdx.y;                  // 0..25
    int tid = threadIdx.x;
    int k = kt * 32 + (tid & 31);
    int n = ng * 8 + (tid >> 5);
    bool live = (k < DD) && (n < DD);
    float vb[BB];
    #pragma unroll
    for (int b = 0; b < BB; ++b)
        vb[b] = live ? bases[((size_t)b * DD + k) * DD + n] : 0.0f;
    size_t wo = (size_t)n * KP + k;
    for (int r = 0; r < RR; ++r) {
        float a = 0.0f;
        #pragma unroll
        for (int b = 0; b < BB; ++b) a += comp[r * BB + b] * vb[b];
        Wt[(size_t)r * (NP * KP) + wo] = f2bf(a);
    }
}

// ---- rootT[n][k] = root[k][n] ----
__global__ void kRootT(const float* __restrict__ root, short* __restrict__ rootT) {
    int idx = blockIdx.x * 256 + threadIdx.x;
    if (idx >= NP * KP) return;
    int n = idx / KP, k = idx - n * KP;
    rootT[idx] = (n < DD && k < DD) ? f2bf(root[k * DD + n]) : (short)0;
}

// ---- shared inner GEMM: NF frags from F0, kc-double-buffered B ----
template<int F0, int NF>
__device__ __forceinline__ void gemmHalf(const short* As, const short* bCol,
                                         int arow, int kg, f32x4* acc) {
    #pragma unroll
    for (int f = 0; f < NF; ++f) acc[f] = (f32x4){0.f, 0.f, 0.f, 0.f};
    bf16x8 bb[2][NF];
    #pragma unroll
    for (int f = 0; f < NF; ++f)
        bb[0][f] = *(const bf16x8*)(bCol + (size_t)(F0 + f) * 16 * KP);
    #pragma unroll
    for (int kc = 0; kc < 7; ++kc) {
        if (kc < 6) {
            #pragma unroll
            for (int f = 0; f < NF; ++f)
                bb[(kc + 1) & 1][f] = *(const bf16x8*)(bCol + (size_t)(F0 + f) * 16 * KP + (kc + 1) * 32);
        }
        bf16x8 a = *(const bf16x8*)(As + arow * AP + kc * 32 + kg);
        #pragma unroll
        for (int f = 0; f < NF; ++f)
            acc[f] = __builtin_amdgcn_mfma_f32_16x16x32_bf16(a, bb[kc & 1][f], acc[f], 0, 0, 0);
    }
}

// ---- y[i][:] = xb[i][:] @ root + bias ----
__global__ __launch_bounds__(256) void kRootGemm(const short* __restrict__ xb,
        const short* __restrict__ rootT, const float* __restrict__ bias,
        float* __restrict__ y) {
    __shared__ short As[TE * AP];
    int i0 = blockIdx.x * TE;
    int tid = threadIdx.x;
    int rowL = tid >> 2, sub = tid & 3;
    int i = i0 + rowL;
    for (int c = sub; c < 29; c += 4) {
        int4 v = make_int4(0, 0, 0, 0);
        if (i < NN && c < 26) v = *(const int4*)(xb + (size_t)i * XP + c * 8);
        *(int4*)(&As[rowL * AP + c * 8]) = v;
    }
    __syncthreads();
    int lane = tid & 63, wave = tid >> 6;
    int stripe = wave * 16;
    int arow = stripe + (lane & 15);
    int kg = (lane >> 4) * 8;
    const short* bCol = rootT + (lane & 15) * KP + kg;
    int colLane = lane & 15;
    int rbase = i0 + stripe + (lane >> 4) * 4;
    {
        f32x4 acc[7];
        gemmHalf<0, 7>(As, bCol, arow, kg, acc);
        #pragma unroll
        for (int f = 0; f < 7; ++f) {
            int col = f * 16 + colLane;
            float bv = bias[col];
            #pragma unroll
            for (int j = 0; j < 4; ++j) {
                int row = rbase + j;
                if (row < NN) y[(size_t)row * DD + col] = acc[f][j] + bv;
            }
        }
    }
    {
        f32x4 acc[6];
        gemmHalf<7, 6>(As, bCol, arow, kg, acc);
        #pragma unroll
        for (int f = 0; f < 6; ++f) {
            int col = (7 + f) * 16 + colLane;
            if (col < DD) {
                float bv = bias[col];
                #pragma unroll
                for (int j = 0; j < 4; ++j) {
                    int row = rbase + j;
                    if (row < NN) y[(size_t)row * DD + col] = acc[f][j] + bv;
                }
            }
        }
    }
}

// ---- per-(bucket,tile) gather-GEMM; MODE 0: store msg rows; MODE 1: atomic y ----
template<int MODE>
__global__ __launch_bounds__(256) void kMsg(const int* __restrict__ ei,
        const short* __restrict__ xb, const short* __restrict__ Wt,
        const int* __restrict__ relStartB, const int* __restrict__ tileOffB,
        const int* __restrict__ sortedE, const float* __restrict__ norm,
        const int* __restrict__ posDst, const int* __restrict__ cesS,
        float* __restrict__ y, short* __restrict__ msg, int c) {
    __shared__ short As[TE * AP];
    __shared__ int   posS[TE];
    __shared__ float normS[TE];
    int tbase = tileOffB[c * RR];
    int tend  = tileOffB[(c + 1) * RR];
    int tileIdx = tbase + blockIdx.x;
    if (tileIdx >= tend) return;
    int lo = c * RR, hi = (c + 1) * RR;
    while (hi - lo > 1) {
        int mid = (lo + hi) >> 1;
        if (tileOffB[mid] <= tileIdx) lo = mid; else hi = mid;
    }
    int bkt = lo;
    int r = bkt - c * RR;
    int eBase = relStartB[bkt] + (tileIdx - tileOffB[bkt]) * TE;
    int eEnd  = relStartB[bkt + 1];
    int tid = threadIdx.x;
    int rowL = tid >> 2, sub = tid & 3;
    int eIdx = eBase + rowL;
    bool valid = eIdx < eEnd;
    int eid = valid ? sortedE[eIdx] : 0;
    if (sub == 0) {
        normS[rowL] = valid ? norm[eid] : 0.0f;
        if (MODE == 0) posS[rowL] = valid ? (posDst[eid] - cesS[c]) : -1;
        else           posS[rowL] = valid ? ei[EE + eid] : -1;
    }
    int srcRow = valid ? ei[eid] : 0;
    for (int cc = sub; cc < 29; cc += 4) {
        int4 v = make_int4(0, 0, 0, 0);
        if (valid && cc < 26) v = *(const int4*)(xb + (size_t)srcRow * XP + cc * 8);
        *(int4*)(&As[rowL * AP + cc * 8]) = v;
    }
    __syncthreads();
    int lane = tid & 63, wave = tid >> 6;
    int stripe = wave * 16;
    int arow = stripe + (lane & 15);
    int kg = (lane >> 4) * 8;
    const short* bCol = Wt + (size_t)r * (NP * KP) + (lane & 15) * KP + kg;
    int colLane = lane & 15;
    int rL0 = stripe + (lane >> 4) * 4;
    {
        f32x4 acc[7];
        gemmHalf<0, 7>(As, bCol, arow, kg, acc);
        #pragma unroll
        for (int j = 0; j < 4; ++j) {
            int rl = rL0 + j;
            float nm = normS[rl];
            int ps = posS[rl];
            if (ps >= 0) {
                #pragma unroll
                for (int f = 0; f < 7; ++f) {
                    int col = f * 16 + colLane;
                    if (MODE == 0) msg[(size_t)ps * MSGP + col] = f2bf(acc[f][j] * nm);
                    else           atomicAdd(&y[(size_t)ps * DD + col], acc[f][j] * nm);
                }
            }
        }
    }
    {
        f32x4 acc[6];
        gemmHalf<7, 6>(As, bCol, arow, kg, acc);
        #pragma unroll
        for (int j = 0; j < 4; ++j) {
            int rl = rL0 + j;
            float nm = normS[rl];
            int ps = posS[rl];
            if (ps >= 0) {
                #pragma unroll
                for (int f = 0; f < 6; ++f) {
                    int col = (7 + f) * 16 + colLane;
                    if (col < DD) {
                        if (MODE == 0) msg[(size_t)ps * MSGP + col] = f2bf(acc[f][j] * nm);
                        else           atomicAdd(&y[(size_t)ps * DD + col], acc[f][j] * nm);
                    }
                }
            }
        }
    }
}

// ---- grid-stride segmented sum over chunk's node range; y = relu(y + sum(msg)) ----
__global__ __launch_bounds__(256) void kAgg(const short* __restrict__ msg,
        const int* __restrict__ dstStart, const int* __restrict__ bS,
        const int* __restrict__ cesS, float* __restrict__ y, int c) {
    int wv = threadIdx.x >> 6, lane = threadIdx.x & 63;
    int b0 = bS[c], b1 = bS[c + 1];
    int ces = cesS[c];
    int gw = blockIdx.x * 4 + wv;
    int nw = gridDim.x * 4;
    for (int d = b0 + gw; d < b1; d += nw) {
        int s = dstStart[d] - ces, e = dstStart[d + 1] - ces;
        float a0 = 0.f, a1 = 0.f, a2 = 0.f, a3 = 0.f;
        if (lane < 50) {
            for (int j = s; j < e; ++j) {
                int2 v = *(const int2*)(msg + (size_t)j * MSGP + lane * 4);
                unsigned u0 = (unsigned)v.x, u1 = (unsigned)v.y;
                a0 += __uint_as_float(u0 << 16);
                a1 += __uint_as_float(u0 & 0xffff0000u);
                a2 += __uint_as_float(u1 << 16);
                a3 += __uint_as_float(u1 & 0xffff0000u);
            }
            int colBase = lane * 4;
            float4 rv = *(const float4*)(y + (size_t)d * DD + colBase);
            float4 o;
            o.x = fmaxf(rv.x + a0, 0.f);
            o.y = fmaxf(rv.y + a1, 0.f);
            o.z = fmaxf(rv.z + a2, 0.f);
            o.w = fmaxf(rv.w + a3, 0.f);
            *(float4*)(y + (size_t)d * DD + colBase) = o;
        }
    }
}

extern "C" void kernel_launch(void* const* d_in, const int* in_sizes, int n_in,
                              void* d_out, int out_size, void* d_ws, size_t ws_size,
                              hipStream_t stream) {
    (void)in_sizes; (void)n_in; (void)out_size;
    const int*   ei    = (const int*)d_in[0];
    const int*   et    = (const int*)d_in[1];
    const float* emb   = (const float*)d_in[2];
    const float* comp  = (const float*)d_in[3];
    const float* bases = (const float*)d_in[4];
    const float* root  = (const float*)d_in[5];
    const float* bias  = (const float*)d_in[6];
    float* y = (float*)d_out;
    char* ws = (char*)d_ws;
    float* norm    = (float*)(ws + OFF_NORM);
    int*   sortedE = (int*)(ws + OFF_SORT);
    short* xb      = (short*)(ws + OFF_XB);
    short* Wt      = (short*)(ws + OFF_WT);
    short* rootT   = (short*)(ws + OFF_ROOTT);
    int*   posDst  = (int*)(ws + OFF_POS);
    int*   dstCnt  = (int*)(ws + OFF_DSTCNT);
    int*   dstStart= (int*)(ws + OFF_DSTST);
    int*   cur     = (int*)(ws + OFF_CUR);
    int*   blockHist = (int*)(ws + OFF_BLKH);
    short* msg     = (short*)(ws + OFF_MSG);
    unsigned int* deg8 = (unsigned int*)(ws + OFF_XB);  // transient alias

    // choose chunk count from available workspace (pure function of ws_size)
    int NC = 0;
    long long T = EE;
    for (int cc = 1; cc <= MAXNC; ++cc) {
        long long t = (EE + cc - 1) / cc;
        if ((unsigned long long)ws_size >= OFF_MSG + (unsigned long long)(t + 64) * (MSGP * 2)) {
            NC = cc; T = t; break;
        }
    }
    int big = (NC > 0) ? 1 : 0;
    if (!big) { NC = 1; T = EE; }

    int *cntB, *relStartB, *cursorB, *tileOffB, *bS, *cesS, *blkSum;
    if (big) {
        int* ctl = (int*)(ws + OFF_CTL);
        cntB = ctl; relStartB = ctl + 3328; cursorB = ctl + 6656;
        tileOffB = ctl + 9984; bS = ctl + 13312; cesS = ctl + 13360; blkSum = ctl + 13440;
    } else {
        int* ctl = (int*)(ws + OFF_CNT);
        cntB = ctl; relStartB = ctl + 256; cursorB = ctl + 512;
        tileOffB = ctl + 768; bS = ctl + 976; cesS = ctl + 992; blkSum = ctl + 1000;
    }

    const int NBLK = (NN + 255) / 256;  // 391

    hipMemsetAsync(deg8, 0, (size_t)NN * RR, stream);
    if (big) {
        hipMemsetAsync(dstCnt, 0, (size_t)NN * 4, stream);
        hipMemsetAsync(cur, 0, (size_t)NN * 4, stream);
    } else {
        hipMemsetAsync((void*)cntB, 0, 4096, stream);
    }

    kCount<<<(EE + 255) / 256, 256, 0, stream>>>(ei, et, deg8, dstCnt, big);
    if (big) {
        kScanBlk<<<NBLK, 256, 0, stream>>>(dstCnt, dstStart, blkSum);
        kScanTop<<<1, 512, 0, stream>>>(blkSum, NBLK);
        kScanAdd<<<NBLK, 256, 0, stream>>>(dstCnt, dstStart, blkSum);
        kChunk<<<1, 64, 0, stream>>>(dstStart, bS, cesS, NC, (int)T);
        // contention-free 2-pass counting sort
        kHist<<<NPART, 256, 0, stream>>>(ei, et, bS, blockHist, NC);
        kScanP<<<NC * RR, 256, 0, stream>>>(blockHist, cntB, NC * RR);
        kScanB<<<1, 256, 0, stream>>>(cntB, relStartB, cursorB, tileOffB, NC * RR);
        kPart<<<NPART, 256, 0, stream>>>(ei, et, deg8, bS, relStartB, blockHist,
                                         dstStart, cur, norm, sortedE, posDst, NC);
    } else {
        kCountB<<<(EE + 255) / 256, 256, 0, stream>>>(ei, et, bS, cntB, NC);
        kScanB<<<1, 256, 0, stream>>>(cntB, relStartB, cursorB, tileOffB, NC * RR);
        kNormScatter<<<(EE + 255) / 256, 256, 0, stream>>>(ei, et, deg8, bS, cursorB,
                                                           dstStart, cur, norm, sortedE,
                                                           posDst, NC, big);
    }
    kConvert<<<(NN * XP + 255) / 256, 256, 0, stream>>>(emb, xb, 0);

    int Gmsg = (int)((T + 64 + 63) / 64) + RR + 4;
    for (int l = 0; l < LL; ++l) {
        kW<<<dim3(7, 26), 256, 0, stream>>>(comp + l * RR * BB,
                                            bases + (size_t)l * BB * DD * DD, Wt);
        kRootT<<<(NP * KP + 255) / 256, 256, 0, stream>>>(root + l * DD * DD, rootT);
        kRootGemm<<<(NN + TE - 1) / TE, 256, 0, stream>>>(xb, rootT, bias + l * DD, y);
        if (big) {
            for (int c = 0; c < NC; ++c) {
                kMsg<0><<<Gmsg, 256, 0, stream>>>(ei, xb, Wt, relStartB, tileOffB,
                                                  sortedE, norm, posDst, cesS, y, msg, c);
                kAgg<<<2048, 256, 0, stream>>>(msg, dstStart, bS, cesS, y, c);
            }
            if (l == 0)
                kConvert<<<(NN * XP + 255) / 256, 256, 0, stream>>>(y, xb, 0);
        } else {
            kMsg<1><<<MAXTILES, 256, 0, stream>>>(ei, xb, Wt, relStartB, tileOffB,
                                                  sortedE, norm, posDst, cesS, y, msg, 0);
            if (l == 0) kConvert<<<(NN * XP + 255) / 256, 256, 0, stream>>>(y, xb, 1);
            else        kRelu<<<(NN * DD + 255) / 256, 256, 0, stream>>>(y);
        }
    }
}

// Round 6
// 1541.481 us; speedup vs baseline: 2.2895x; 1.0248x over previous
//
#include <hip/hip_runtime.h>
#include <hip/hip_bf16.h>
#include <stdint.h>

// Problem constants
#define NN 100000   // nodes
#define RR 200      // relations
#define DD 200      // dim
#define BB 30       // bases
#define LL 2        // layers
#define EE 800000   // edges

// Padded GEMM geometry
#define KP 224      // K padded (7 x 32)
#define NP 208      // N padded (13 x 16)
#define XP 208      // xb row pitch (bf16)
#define AP 232      // LDS A-tile pitch (bf16)
#define TE 128      // edges per tile (2 M-frags per wave)
#define MSGP 200    // msg row pitch (bf16) -> 400B
#define MAXTILES 6700
#define MAXNC 16
#define NPART 256   // partition blocks for the 2-pass sort
#define EPB ((EE + NPART - 1) / NPART)   // 3125 edges per partition

using bf16x8 = __attribute__((ext_vector_type(8))) short;
using f32x4  = __attribute__((ext_vector_type(4))) float;

// Workspace layout. Fallback path touches only < OFF_CTL.
#define OFF_NORM   0ull          // E f32
#define OFF_SORT   3200000ull    // E i32
#define OFF_CNT    6400000ull    // 4KB ctl (fallback)
#define OFF_XB     6404096ull    // N*XP bf16 (deg8 20MB aliases transiently)
#define OFF_WT     48004096ull   // R*NP*KP bf16
#define OFF_ROOTT  66640896ull   // NP*KP bf16
#define OFF_CTL    66734080ull   // 64KB ctl (big)
#define OFF_POS    66799616ull   // E i32
#define OFF_DSTCNT 69999616ull   // N i32
#define OFF_DSTST  70399616ull   // (N+1) i32 (+pad)
#define OFF_CUR    70799632ull   // N i32
#define OFF_BLKH   71199632ull   // NPART * MAXNC*RR i32 = 3,276,800
#define OFF_MSG    74476432ull   // chunk msg buffer, (T+64)*MSGP*2 bytes

static __device__ __forceinline__ short f2bf(float v) {
    union { __hip_bfloat16 h; short s; } u;
    u.h = __float2bfloat16(v);
    return u.s;
}

// ---- deg per (dst,rel) + per-dst histogram ----
__global__ void kCount(const int* __restrict__ ei, const int* __restrict__ et,
                       unsigned int* __restrict__ deg8, int* __restrict__ dstCnt, int big) {
    int e = blockIdx.x * 256 + threadIdx.x;
    if (e >= EE) return;
    int d = ei[EE + e];
    int t = et[e];
    int comb = d * RR + t;
    atomicAdd(&deg8[comb >> 2], 1u << ((comb & 3) * 8));
    if (big) atomicAdd(&dstCnt[d], 1);
}

// ---- 3-kernel exclusive scan of dstCnt[N] -> dstStart[N+1] ----
__global__ void kScanBlk(const int* __restrict__ dstCnt, int* __restrict__ dstStart,
                         int* __restrict__ blkSum) {
    __shared__ int s[256];
    int t = threadIdx.x, i = blockIdx.x * 256 + t;
    int v = (i < NN) ? dstCnt[i] : 0;
    s[t] = v;
    __syncthreads();
    #pragma unroll
    for (int off = 1; off < 256; off <<= 1) {
        int x = (t >= off) ? s[t - off] : 0;
        __syncthreads();
        s[t] += x;
        __syncthreads();
    }
    if (i < NN) dstStart[i] = s[t] - v;
    if (t == 255) blkSum[blockIdx.x] = s[255];
}
__global__ void kScanTop(int* __restrict__ blkSum, int nblk) {
    __shared__ int s[512];
    int t = threadIdx.x;
    int v = (t < nblk) ? blkSum[t] : 0;
    s[t] = v;
    __syncthreads();
    #pragma unroll
    for (int off = 1; off < 512; off <<= 1) {
        int x = (t >= off) ? s[t - off] : 0;
        __syncthreads();
        s[t] += x;
        __syncthreads();
    }
    if (t < nblk) blkSum[t] = s[t] - v;
}
__global__ void kScanAdd(const int* __restrict__ dstCnt, int* __restrict__ dstStart,
                         const int* __restrict__ blkSum) {
    int i = blockIdx.x * 256 + threadIdx.x;
    if (i >= NN) return;
    int v = dstStart[i] + blkSum[blockIdx.x];
    dstStart[i] = v;
    if (i == NN - 1) dstStart[NN] = v + dstCnt[i];
}

// ---- chunk boundaries: b[c] = smallest node with dstStart >= c*T ----
__global__ void kChunk(const int* __restrict__ dstStart, int* __restrict__ bS,
                       int* __restrict__ cesS, int NC, int T) {
    int tid = threadIdx.x;
    if (tid > NC) return;
    int v;
    if (tid == NC) v = NN;
    else if (tid == 0) v = 0;
    else {
        int target = tid * T;
        int lo = 0, hi = NN;
        while (lo < hi) {
            int mid = (lo + hi) >> 1;
            if (dstStart[mid] >= target) hi = mid; else lo = mid + 1;
        }
        v = lo;
    }
    bS[tid] = v;
    cesS[tid] = dstStart[v];
}

// ---- PASS 1: per-partition LDS histogram of (chunk,rel) buckets ----
__global__ __launch_bounds__(256) void kHist(const int* __restrict__ ei,
        const int* __restrict__ et, const int* __restrict__ bS,
        int* __restrict__ blockHist, int NC) {
    __shared__ int hist[MAXNC * RR];
    __shared__ int bsh[MAXNC + 1];
    int tid = threadIdx.x, b = blockIdx.x;
    int NB = NC * RR;
    if (tid <= NC) bsh[tid] = bS[tid];
    for (int i = tid; i < NB; i += 256) hist[i] = 0;
    __syncthreads();
    int ebeg = b * EPB, eend = min(EE, ebeg + EPB);
    for (int e = ebeg + tid; e < eend; e += 256) {
        int d = ei[EE + e];
        int t = et[e];
        int c = 0;
        for (int j = 1; j < NC; ++j) if (d >= bsh[j]) c = j;
        atomicAdd(&hist[c * RR + t], 1);
    }
    __syncthreads();
    for (int i = tid; i < NB; i += 256)
        blockHist[(size_t)b * NB + i] = hist[i];
}

// ---- PASS 1b: per-bucket exclusive scan across partitions; totals -> cntB ----
__global__ __launch_bounds__(256) void kScanP(int* __restrict__ blockHist,
                                              int* __restrict__ cntB, int NB) {
    __shared__ int s[256];
    int t = threadIdx.x, k = blockIdx.x;
    int v = blockHist[(size_t)t * NB + k];
    s[t] = v;
    __syncthreads();
    #pragma unroll
    for (int off = 1; off < 256; off <<= 1) {
        int x = (t >= off) ? s[t - off] : 0;
        __syncthreads();
        s[t] += x;
        __syncthreads();
    }
    blockHist[(size_t)t * NB + k] = s[t] - v;
    if (t == 255) cntB[k] = s[255];
}

// ---- bucket scan (nb <= 3200) ----
__global__ void kScanB(const int* __restrict__ cntB, int* __restrict__ relStartB,
                       int* __restrict__ cursorB, int* __restrict__ tileOffB, int nb) {
    __shared__ int c[MAXNC * RR];
    __shared__ int rs[MAXNC * RR + 1];
    __shared__ int to[MAXNC * RR + 1];
    int tid = threadIdx.x;
    for (int i = tid; i < nb; i += 256) c[i] = cntB[i];
    __syncthreads();
    if (tid == 0) {
        int s = 0, ts = 0;
        for (int i = 0; i < nb; ++i) {
            rs[i] = s; to[i] = ts;
            s += c[i];
            ts += (c[i] + TE - 1) / TE;
        }
        rs[nb] = s; to[nb] = ts;
    }
    __syncthreads();
    for (int i = tid; i <= nb; i += 256) {
        relStartB[i] = rs[i];
        tileOffB[i]  = to[i];
        if (i < nb) cursorB[i] = rs[i];
    }
}

// ---- PASS 2: partition scatter with LDS cursors; norm + posDst fused ----
__global__ __launch_bounds__(256) void kPart(const int* __restrict__ ei,
        const int* __restrict__ et, const unsigned int* __restrict__ deg8,
        const int* __restrict__ bS, const int* __restrict__ relStartB,
        const int* __restrict__ blockHist, const int* __restrict__ dstStart,
        int* __restrict__ cur, float* __restrict__ norm, int* __restrict__ sortedE,
        int* __restrict__ posDst, int NC) {
    __shared__ int curL[MAXNC * RR];
    __shared__ int bsh[MAXNC + 1];
    int tid = threadIdx.x, b = blockIdx.x;
    int NB = NC * RR;
    if (tid <= NC) bsh[tid] = bS[tid];
    for (int i = tid; i < NB; i += 256)
        curL[i] = relStartB[i] + blockHist[(size_t)b * NB + i];
    __syncthreads();
    int ebeg = b * EPB, eend = min(EE, ebeg + EPB);
    for (int e = ebeg + tid; e < eend; e += 256) {
        int d = ei[EE + e];
        int t = et[e];
        int comb = d * RR + t;
        unsigned int deg = (deg8[comb >> 2] >> ((comb & 3) * 8)) & 0xffu;
        norm[e] = 1.0f / (float)(deg ? deg : 1u);
        int c = 0;
        for (int j = 1; j < NC; ++j) if (d >= bsh[j]) c = j;
        int pos = atomicAdd(&curL[c * RR + t], 1);
        sortedE[pos] = e;
        posDst[e] = dstStart[d] + atomicAdd(&cur[d], 1);
    }
}

// ---- fallback-only: (chunk, rel) bucket histogram via global atomics ----
__global__ void kCountB(const int* __restrict__ ei, const int* __restrict__ et,
                        const int* __restrict__ bS, int* __restrict__ cntB, int NC) {
    __shared__ int bsh[MAXNC + 1];
    if (threadIdx.x <= NC) bsh[threadIdx.x] = bS[threadIdx.x];
    __syncthreads();
    int e = blockIdx.x * 256 + threadIdx.x;
    if (e >= EE) return;
    int d = ei[EE + e];
    int t = et[e];
    int c = 0;
    for (int j = 1; j < NC; ++j) if (d >= bsh[j]) c = j;
    atomicAdd(&cntB[c * RR + t], 1);
}

// ---- fallback-only: per-edge norm + counting-sort via global cursors ----
__global__ void kNormScatter(const int* __restrict__ ei, const int* __restrict__ et,
                             const unsigned int* __restrict__ deg8, const int* __restrict__ bS,
                             int* __restrict__ cursorB, const int* __restrict__ dstStart,
                             int* __restrict__ cur, float* __restrict__ norm,
                             int* __restrict__ sortedE, int* __restrict__ posDst,
                             int NC, int big) {
    __shared__ int bsh[MAXNC + 1];
    if (threadIdx.x <= NC) bsh[threadIdx.x] = bS[threadIdx.x];
    __syncthreads();
    int e = blockIdx.x * 256 + threadIdx.x;
    if (e >= EE) return;
    int d = ei[EE + e];
    int t = et[e];
    int comb = d * RR + t;
    unsigned int deg = (deg8[comb >> 2] >> ((comb & 3) * 8)) & 0xffu;
    norm[e] = 1.0f / (float)(deg ? deg : 1u);
    int c = 0;
    for (int j = 1; j < NC; ++j) if (d >= bsh[j]) c = j;
    int pos = atomicAdd(&cursorB[c * RR + t], 1);
    sortedE[pos] = e;
    if (big) posDst[e] = dstStart[d] + atomicAdd(&cur[d], 1);
}

// ---- fp32 [N,DD] -> bf16 [N,XP] ----
__global__ void kConvert(const float* __restrict__ x, short* __restrict__ xb, int doRelu) {
    int idx = blockIdx.x * 256 + threadIdx.x;
    if (idx >= NN * XP) return;
    int i = idx / XP, col = idx - i * XP;
    float v = 0.0f;
    if (col < DD) {
        v = x[i * DD + col];
        if (doRelu) v = fmaxf(v, 0.0f);
    }
    xb[idx] = (col < DD) ? f2bf(v) : (short)0;
}

__global__ void kRelu(float* __restrict__ y) {
    int idx = blockIdx.x * 256 + threadIdx.x;
    if (idx < NN * DD) y[idx] = fmaxf(y[idx], 0.0f);
}

// ---- Wt[r][n][k] = sum_b comp[r][b]*bases[b][k][n]; load-once-per-cell ----
__global__ __launch_bounds__(256) void kW(const float* __restrict__ comp,
                                          const float* __restrict__ bases,
                                          short* __restrict__ Wt) {
    int kt = blockIdx.x;                  // 0..6
    int ng = blockIdx.y;                  // 0..25
    int tid = threadIdx.x;
    int k = kt * 32 + (tid & 31);
    int n = ng * 8 + (tid >> 5);
    bool live = (k < DD) && (n < DD);
    float vb[BB];
    #pragma unroll
    for (int b = 0; b < BB; ++b)
        vb[b] = live ? bases[((size_t)b * DD + k) * DD + n] : 0.0f;
    size_t wo = (size_t)n * KP + k;
    for (int r = 0; r < RR; ++r) {
        float a = 0.0f;
        #pragma unroll
        for (int b = 0; b < BB; ++b) a += comp[r * BB + b] * vb[b];
        Wt[(size_t)r * (NP * KP) + wo] = f2bf(a);
    }
}

// ---- rootT[n][k] = root[k][n] ----
__global__ void kRootT(const float* __restrict__ root, short* __restrict__ rootT) {
    int idx = blockIdx.x * 256 + threadIdx.x;
    if (idx >= NP * KP) return;
    int n = idx / KP, k = idx - n * KP;
    rootT[idx] = (n < DD && k < DD) ? f2bf(root[k * DD + n]) : (short)0;
}

// ---- inner GEMM: 2 M-frags x NF N-frags from F0, kc-double-buffered B ----
template<int F0, int NF>
__device__ __forceinline__ void gemmHalf2(const short* As, const short* bCol,
                                          int arow0, int arow1, int kg,
                                          f32x4* acc0, f32x4* acc1) {
    #pragma unroll
    for (int f = 0; f < NF; ++f) {
        acc0[f] = (f32x4){0.f, 0.f, 0.f, 0.f};
        acc1[f] = (f32x4){0.f, 0.f, 0.f, 0.f};
    }
    bf16x8 bb[2][NF];
    #pragma unroll
    for (int f = 0; f < NF; ++f)
        bb[0][f] = *(const bf16x8*)(bCol + (size_t)(F0 + f) * 16 * KP);
    #pragma unroll
    for (int kc = 0; kc < 7; ++kc) {
        if (kc < 6) {
            #pragma unroll
            for (int f = 0; f < NF; ++f)
                bb[(kc + 1) & 1][f] = *(const bf16x8*)(bCol + (size_t)(F0 + f) * 16 * KP + (kc + 1) * 32);
        }
        bf16x8 a0 = *(const bf16x8*)(&As[arow0 * AP + kc * 32 + kg]);
        bf16x8 a1 = *(const bf16x8*)(&As[arow1 * AP + kc * 32 + kg]);
        #pragma unroll
        for (int f = 0; f < NF; ++f) {
            acc0[f] = __builtin_amdgcn_mfma_f32_16x16x32_bf16(a0, bb[kc & 1][f], acc0[f], 0, 0, 0);
            acc1[f] = __builtin_amdgcn_mfma_f32_16x16x32_bf16(a1, bb[kc & 1][f], acc1[f], 0, 0, 0);
        }
    }
}

// ---- y[i][:] = xb[i][:] @ root + bias  (128 rows/block, 2 M-frags/wave) ----
__global__ __launch_bounds__(256) void kRootGemm(const short* __restrict__ xb,
        const short* __restrict__ rootT, const float* __restrict__ bias,
        float* __restrict__ y) {
    __shared__ short As[TE * AP];
    int i0 = blockIdx.x * TE;
    int tid = threadIdx.x;
    int rowL = tid >> 1, sub = tid & 1;
    int i = i0 + rowL;
    for (int c = sub; c < 29; c += 2) {
        int4 v = make_int4(0, 0, 0, 0);
        if (i < NN && c < 26) v = *(const int4*)(xb + (size_t)i * XP + c * 8);
        *(int4*)(&As[rowL * AP + c * 8]) = v;
    }
    __syncthreads();
    int lane = tid & 63, wave = tid >> 6;
    int arow0 = wave * 32 + (lane & 15);
    int arow1 = arow0 + 16;
    int kg = (lane >> 4) * 8;
    const short* bCol = rootT + (lane & 15) * KP + kg;
    int colLane = lane & 15;
    int rbase = i0 + wave * 32 + (lane >> 4) * 4;
    {
        f32x4 acc0[7], acc1[7];
        gemmHalf2<0, 7>(As, bCol, arow0, arow1, kg, acc0, acc1);
        #pragma unroll
        for (int f = 0; f < 7; ++f) {
            int col = f * 16 + colLane;
            float bv = bias[col];
            #pragma unroll
            for (int j = 0; j < 4; ++j) {
                int r0 = rbase + j, r1 = rbase + 16 + j;
                if (r0 < NN) y[(size_t)r0 * DD + col] = acc0[f][j] + bv;
                if (r1 < NN) y[(size_t)r1 * DD + col] = acc1[f][j] + bv;
            }
        }
    }
    {
        f32x4 acc0[6], acc1[6];
        gemmHalf2<7, 6>(As, bCol, arow0, arow1, kg, acc0, acc1);
        #pragma unroll
        for (int f = 0; f < 6; ++f) {
            int col = (7 + f) * 16 + colLane;
            if (col < DD) {
                float bv = bias[col];
                #pragma unroll
                for (int j = 0; j < 4; ++j) {
                    int r0 = rbase + j, r1 = rbase + 16 + j;
                    if (r0 < NN) y[(size_t)r0 * DD + col] = acc0[f][j] + bv;
                    if (r1 < NN) y[(size_t)r1 * DD + col] = acc1[f][j] + bv;
                }
            }
        }
    }
}

// ---- per-(bucket,tile) gather-GEMM; MODE 0: store msg rows; MODE 1: atomic y ----
template<int MODE>
__global__ __launch_bounds__(256) void kMsg(const int* __restrict__ ei,
        const short* __restrict__ xb, const short* __restrict__ Wt,
        const int* __restrict__ relStartB, const int* __restrict__ tileOffB,
        const int* __restrict__ sortedE, const float* __restrict__ norm,
        const int* __restrict__ posDst, const int* __restrict__ cesS,
        float* __restrict__ y, short* __restrict__ msg, int c) {
    __shared__ short As[TE * AP];
    __shared__ int   posS[TE];
    __shared__ float normS[TE];
    int tbase = tileOffB[c * RR];
    int tend  = tileOffB[(c + 1) * RR];
    int tileIdx = tbase + blockIdx.x;
    if (tileIdx >= tend) return;
    int lo = c * RR, hi = (c + 1) * RR;
    while (hi - lo > 1) {
        int mid = (lo + hi) >> 1;
        if (tileOffB[mid] <= tileIdx) lo = mid; else hi = mid;
    }
    int bkt = lo;
    int r = bkt - c * RR;
    int eBase = relStartB[bkt] + (tileIdx - tileOffB[bkt]) * TE;
    int eEnd  = relStartB[bkt + 1];
    int tid = threadIdx.x;
    int rowL = tid >> 1, sub = tid & 1;
    int eIdx = eBase + rowL;
    bool valid = eIdx < eEnd;
    int eid = valid ? sortedE[eIdx] : 0;
    if (sub == 0) {
        normS[rowL] = valid ? norm[eid] : 0.0f;
        if (MODE == 0) posS[rowL] = valid ? (posDst[eid] - cesS[c]) : -1;
        else           posS[rowL] = valid ? ei[EE + eid] : -1;
    }
    int srcRow = valid ? ei[eid] : 0;
    for (int cc = sub; cc < 29; cc += 2) {
        int4 v = make_int4(0, 0, 0, 0);
        if (valid && cc < 26) v = *(const int4*)(xb + (size_t)srcRow * XP + cc * 8);
        *(int4*)(&As[rowL * AP + cc * 8]) = v;
    }
    __syncthreads();
    int lane = tid & 63, wave = tid >> 6;
    int arow0 = wave * 32 + (lane & 15);
    int arow1 = arow0 + 16;
    int kg = (lane >> 4) * 8;
    const short* bCol = Wt + (size_t)r * (NP * KP) + (lane & 15) * KP + kg;
    int colLane = lane & 15;
    int rL0 = wave * 32 + (lane >> 4) * 4;
    {
        f32x4 acc0[7], acc1[7];
        gemmHalf2<0, 7>(As, bCol, arow0, arow1, kg, acc0, acc1);
        #pragma unroll
        for (int j = 0; j < 4; ++j) {
            #pragma unroll
            for (int m = 0; m < 2; ++m) {
                int rl = rL0 + m * 16 + j;
                float nm = normS[rl];
                int ps = posS[rl];
                if (ps >= 0) {
                    #pragma unroll
                    for (int f = 0; f < 7; ++f) {
                        int col = f * 16 + colLane;
                        float val = (m ? acc1[f][j] : acc0[f][j]) * nm;
                        if (MODE == 0) msg[(size_t)ps * MSGP + col] = f2bf(val);
                        else           atomicAdd(&y[(size_t)ps * DD + col], val);
                    }
                }
            }
        }
    }
    {
        f32x4 acc0[6], acc1[6];
        gemmHalf2<7, 6>(As, bCol, arow0, arow1, kg, acc0, acc1);
        #pragma unroll
        for (int j = 0; j < 4; ++j) {
            #pragma unroll
            for (int m = 0; m < 2; ++m) {
                int rl = rL0 + m * 16 + j;
                float nm = normS[rl];
                int ps = posS[rl];
                if (ps >= 0) {
                    #pragma unroll
                    for (int f = 0; f < 6; ++f) {
                        int col = (7 + f) * 16 + colLane;
                        if (col < DD) {
                            float val = (m ? acc1[f][j] : acc0[f][j]) * nm;
                            if (MODE == 0) msg[(size_t)ps * MSGP + col] = f2bf(val);
                            else           atomicAdd(&y[(size_t)ps * DD + col], val);
                        }
                    }
                }
            }
        }
    }
}

// ---- grid-stride segmented sum over chunk's node range; y = relu(y + sum(msg)) ----
__global__ __launch_bounds__(256) void kAgg(const short* __restrict__ msg,
        const int* __restrict__ dstStart, const int* __restrict__ bS,
        const int* __restrict__ cesS, float* __restrict__ y, int c) {
    int wv = threadIdx.x >> 6, lane = threadIdx.x & 63;
    int b0 = bS[c], b1 = bS[c + 1];
    int ces = cesS[c];
    int gw = blockIdx.x * 4 + wv;
    int nw = gridDim.x * 4;
    for (int d = b0 + gw; d < b1; d += nw) {
        int s = dstStart[d] - ces, e = dstStart[d + 1] - ces;
        float a0 = 0.f, a1 = 0.f, a2 = 0.f, a3 = 0.f;
        if (lane < 50) {
            for (int j = s; j < e; ++j) {
                int2 v = *(const int2*)(msg + (size_t)j * MSGP + lane * 4);
                unsigned u0 = (unsigned)v.x, u1 = (unsigned)v.y;
                a0 += __uint_as_float(u0 << 16);
                a1 += __uint_as_float(u0 & 0xffff0000u);
                a2 += __uint_as_float(u1 << 16);
                a3 += __uint_as_float(u1 & 0xffff0000u);
            }
            int colBase = lane * 4;
            float4 rv = *(const float4*)(y + (size_t)d * DD + colBase);
            float4 o;
            o.x = fmaxf(rv.x + a0, 0.f);
            o.y = fmaxf(rv.y + a1, 0.f);
            o.z = fmaxf(rv.z + a2, 0.f);
            o.w = fmaxf(rv.w + a3, 0.f);
            *(float4*)(y + (size_t)d * DD + colBase) = o;
        }
    }
}

extern "C" void kernel_launch(void* const* d_in, const int* in_sizes, int n_in,
                              void* d_out, int out_size, void* d_ws, size_t ws_size,
                              hipStream_t stream) {
    (void)in_sizes; (void)n_in; (void)out_size;
    const int*   ei    = (const int*)d_in[0];
    const int*   et    = (const int*)d_in[1];
    const float* emb   = (const float*)d_in[2];
    const float* comp  = (const float*)d_in[3];
    const float* bases = (const float*)d_in[4];
    const float* root  = (const float*)d_in[5];
    const float* bias  = (const float*)d_in[6];
    float* y = (float*)d_out;
    char* ws = (char*)d_ws;
    float* norm    = (float*)(ws + OFF_NORM);
    int*   sortedE = (int*)(ws + OFF_SORT);
    short* xb      = (short*)(ws + OFF_XB);
    short* Wt      = (short*)(ws + OFF_WT);
    short* rootT   = (short*)(ws + OFF_ROOTT);
    int*   posDst  = (int*)(ws + OFF_POS);
    int*   dstCnt  = (int*)(ws + OFF_DSTCNT);
    int*   dstStart= (int*)(ws + OFF_DSTST);
    int*   cur     = (int*)(ws + OFF_CUR);
    int*   blockHist = (int*)(ws + OFF_BLKH);
    short* msg     = (short*)(ws + OFF_MSG);
    unsigned int* deg8 = (unsigned int*)(ws + OFF_XB);  // transient alias

    // choose chunk count from available workspace (pure function of ws_size)
    int NC = 0;
    long long T = EE;
    for (int cc = 1; cc <= MAXNC; ++cc) {
        long long t = (EE + cc - 1) / cc;
        if ((unsigned long long)ws_size >= OFF_MSG + (unsigned long long)(t + 64) * (MSGP * 2)) {
            NC = cc; T = t; break;
        }
    }
    int big = (NC > 0) ? 1 : 0;
    if (!big) { NC = 1; T = EE; }

    int *cntB, *relStartB, *cursorB, *tileOffB, *bS, *cesS, *blkSum;
    if (big) {
        int* ctl = (int*)(ws + OFF_CTL);
        cntB = ctl; relStartB = ctl + 3328; cursorB = ctl + 6656;
        tileOffB = ctl + 9984; bS = ctl + 13312; cesS = ctl + 13360; blkSum = ctl + 13440;
    } else {
        int* ctl = (int*)(ws + OFF_CNT);
        cntB = ctl; relStartB = ctl + 256; cursorB = ctl + 512;
        tileOffB = ctl + 768; bS = ctl + 976; cesS = ctl + 992; blkSum = ctl + 1000;
    }

    const int NBLK = (NN + 255) / 256;  // 391

    hipMemsetAsync(deg8, 0, (size_t)NN * RR, stream);
    if (big) {
        hipMemsetAsync(dstCnt, 0, (size_t)NN * 4, stream);
        hipMemsetAsync(cur, 0, (size_t)NN * 4, stream);
    } else {
        hipMemsetAsync((void*)cntB, 0, 4096, stream);
    }

    kCount<<<(EE + 255) / 256, 256, 0, stream>>>(ei, et, deg8, dstCnt, big);
    if (big) {
        kScanBlk<<<NBLK, 256, 0, stream>>>(dstCnt, dstStart, blkSum);
        kScanTop<<<1, 512, 0, stream>>>(blkSum, NBLK);
        kScanAdd<<<NBLK, 256, 0, stream>>>(dstCnt, dstStart, blkSum);
        kChunk<<<1, 64, 0, stream>>>(dstStart, bS, cesS, NC, (int)T);
        // contention-free 2-pass counting sort
        kHist<<<NPART, 256, 0, stream>>>(ei, et, bS, blockHist, NC);
        kScanP<<<NC * RR, 256, 0, stream>>>(blockHist, cntB, NC * RR);
        kScanB<<<1, 256, 0, stream>>>(cntB, relStartB, cursorB, tileOffB, NC * RR);
        kPart<<<NPART, 256, 0, stream>>>(ei, et, deg8, bS, relStartB, blockHist,
                                         dstStart, cur, norm, sortedE, posDst, NC);
    } else {
        kCountB<<<(EE + 255) / 256, 256, 0, stream>>>(ei, et, bS, cntB, NC);
        kScanB<<<1, 256, 0, stream>>>(cntB, relStartB, cursorB, tileOffB, NC * RR);
        kNormScatter<<<(EE + 255) / 256, 256, 0, stream>>>(ei, et, deg8, bS, cursorB,
                                                           dstStart, cur, norm, sortedE,
                                                           posDst, NC, big);
    }
    kConvert<<<(NN * XP + 255) / 256, 256, 0, stream>>>(emb, xb, 0);

    int Gmsg = (int)((T + TE - 1) / TE) + RR + 4;
    for (int l = 0; l < LL; ++l) {
        kW<<<dim3(7, 26), 256, 0, stream>>>(comp + l * RR * BB,
                                            bases + (size_t)l * BB * DD * DD, Wt);
        kRootT<<<(NP * KP + 255) / 256, 256, 0, stream>>>(root + l * DD * DD, rootT);
        kRootGemm<<<(NN + TE - 1) / TE, 256, 0, stream>>>(xb, rootT, bias + l * DD, y);
        if (big) {
            for (int c = 0; c < NC; ++c) {
                kMsg<0><<<Gmsg, 256, 0, stream>>>(ei, xb, Wt, relStartB, tileOffB,
                                                  sortedE, norm, posDst, cesS, y, msg, c);
                kAgg<<<2048, 256, 0, stream>>>(msg, dstStart, bS, cesS, y, c);
            }
            if (l == 0)
                kConvert<<<(NN * XP + 255) / 256, 256, 0, stream>>>(y, xb, 0);
        } else {
            kMsg<1><<<MAXTILES, 256, 0, stream>>>(ei, xb, Wt, relStartB, tileOffB,
                                                  sortedE, norm, posDst, cesS, y, msg, 0);
            if (l == 0) kConvert<<<(NN * XP + 255) / 256, 256, 0, stream>>>(y, xb, 1);
            else        kRelu<<<(NN * DD + 255) / 256, 256, 0, stream>>>(y);
        }
    }
}